// Round 2
// baseline (1504.752 us; speedup 1.0000x reference)
//
#include <hip/hip_runtime.h>
#include <hip/hip_bf16.h>
#include <math.h>

#define D_MODEL 1024
#define N_HEADS 16
#define HEAD_DIM 64
#define SEQ1 1536
#define SEQ2 512
#define NTOT 2048
#define BATCH 2

// ---------------------------------------------------------------------------
// GEMM: C[M,N] = A[M,K] @ W[N,K]^T + bias[N]
// 128x128 tile, BK=16, 256 threads, 8x8 per thread as 2x2 blocks of 4x4.
// Requires M%128==0, N%128==0, K%16==0 (true for all launches here).
// ---------------------------------------------------------------------------
#define BM 128
#define BN 128
#define BK 16
#define LDT 132  // padded LDS row stride (dwords), multiple of 4 for float4

__global__ __launch_bounds__(256) void gemm_bias(
    const float* __restrict__ A, const float* __restrict__ W,
    const float* __restrict__ bias, float* __restrict__ C,
    int M, int N, int K)
{
  __shared__ float As[BK][LDT];
  __shared__ float Bs[BK][LDT];
  const int tid = threadIdx.x;
  const int tx = tid & 15, ty = tid >> 4;
  const int m0 = blockIdx.y * BM, n0 = blockIdx.x * BN;

  float acc[2][2][4][4] = {};

  const float* Ap = A + (size_t)m0 * K;
  const float* Wp = W + (size_t)n0 * K;

  for (int k0 = 0; k0 < K; k0 += BK) {
#pragma unroll
    for (int l = 0; l < 2; ++l) {
      int idx = tid + l * 256;          // 0..511
      int row = idx >> 2;               // 0..127
      int kv  = (idx & 3) << 2;         // 0,4,8,12
      float4 a = *(const float4*)(Ap + (size_t)row * K + k0 + kv);
      As[kv + 0][row] = a.x; As[kv + 1][row] = a.y;
      As[kv + 2][row] = a.z; As[kv + 3][row] = a.w;
      float4 b = *(const float4*)(Wp + (size_t)row * K + k0 + kv);
      Bs[kv + 0][row] = b.x; Bs[kv + 1][row] = b.y;
      Bs[kv + 2][row] = b.z; Bs[kv + 3][row] = b.w;
    }
    __syncthreads();
#pragma unroll
    for (int kk = 0; kk < BK; ++kk) {
      float a0[4], a1[4], b0[4], b1[4];
      *(float4*)a0 = *(const float4*)&As[kk][ty * 4];
      *(float4*)a1 = *(const float4*)&As[kk][64 + ty * 4];
      *(float4*)b0 = *(const float4*)&Bs[kk][tx * 4];
      *(float4*)b1 = *(const float4*)&Bs[kk][64 + tx * 4];
#pragma unroll
      for (int i = 0; i < 4; ++i)
#pragma unroll
        for (int j = 0; j < 4; ++j) {
          acc[0][0][i][j] += a0[i] * b0[j];
          acc[0][1][i][j] += a0[i] * b1[j];
          acc[1][0][i][j] += a1[i] * b0[j];
          acc[1][1][i][j] += a1[i] * b1[j];
        }
    }
    __syncthreads();
  }

#pragma unroll
  for (int bi = 0; bi < 2; ++bi)
#pragma unroll
    for (int i = 0; i < 4; ++i) {
      int r = m0 + bi * 64 + ty * 4 + i;
#pragma unroll
      for (int bj = 0; bj < 2; ++bj) {
        int c = n0 + bj * 64 + tx * 4;
        float4 o;
        o.x = acc[bi][bj][i][0] + bias[c + 0];
        o.y = acc[bi][bj][i][1] + bias[c + 1];
        o.z = acc[bi][bj][i][2] + bias[c + 2];
        o.w = acc[bi][bj][i][3] + bias[c + 3];
        *(float4*)(C + (size_t)r * N + c) = o;
      }
    }
}

// ---------------------------------------------------------------------------
// RMSNorm + RoPE + scatter into (B, H, NTOT, 64) q/k/v buffers.
// One block (256 thr = 4 waves) per token row; one wave (=64 lanes = head_dim)
// per head.
// ---------------------------------------------------------------------------
__global__ __launch_bounds__(256) void qkv_transform(
    const float* __restrict__ qkv1, const float* __restrict__ qkv2,
    const float* __restrict__ qs1, const float* __restrict__ ks1,
    const float* __restrict__ qs2, const float* __restrict__ ks2,
    float* __restrict__ qO, float* __restrict__ kO, float* __restrict__ vO)
{
  const int row = blockIdx.x;                 // 0..4095
  const int lane = threadIdx.x & 63;
  const int wave = threadIdx.x >> 6;

  const float* src;
  const float* qs;
  const float* ks;
  int b, pos;
  if (row < BATCH * SEQ1) {
    b = row / SEQ1;
    int n = row % SEQ1;
    pos = n;                                   // concat position == rope pos
    src = qkv1 + (size_t)row * (3 * D_MODEL);
    qs = qs1; ks = ks1;
  } else {
    int r2 = row - BATCH * SEQ1;
    b = r2 / SEQ2;
    int n = r2 % SEQ2;
    pos = SEQ1 + n;
    src = qkv2 + (size_t)r2 * (3 * D_MODEL);
    qs = qs2; ks = ks2;
  }

  // rope angle for this lane's pair
  const int j = lane >> 1;
  const float LOG2_THETA = 13.287712379549449f;      // log2(10000)
  float inv_freq = exp2f(-((float)(2 * j) / 64.0f) * LOG2_THETA);
  float ang = (float)pos * inv_freq;
  float sn, cs;
  sincosf(ang, &sn, &cs);

  for (int h = wave; h < N_HEADS; h += 4) {
    float xq = src[0 * D_MODEL + h * HEAD_DIM + lane];
    float xk = src[1 * D_MODEL + h * HEAD_DIM + lane];
    float xv = src[2 * D_MODEL + h * HEAD_DIM + lane];

    // RMS over 64 lanes (one wave)
    float sq = xq * xq;
    float sk = xk * xk;
#pragma unroll
    for (int o = 32; o > 0; o >>= 1) {
      sq += __shfl_xor(sq, o);
      sk += __shfl_xor(sk, o);
    }
    float xqn = xq * rsqrtf(sq * (1.0f / 64.0f) + 1e-6f) * qs[lane];
    float xkn = xk * rsqrtf(sk * (1.0f / 64.0f) + 1e-6f) * ks[lane];

    // interleaved rope: pairs (even, odd)
    float pq = __shfl_xor(xqn, 1);
    float pk = __shfl_xor(xkn, 1);
    float oq, ok;
    if (lane & 1) {                // odd: r2 = x1*sin + x2*cos ; x1=partner
      oq = pq * sn + xqn * cs;
      ok = pk * sn + xkn * cs;
    } else {                       // even: r1 = x1*cos - x2*sin ; x2=partner
      oq = xqn * cs - pq * sn;
      ok = xkn * cs - pk * sn;
    }

    size_t o = (((size_t)b * N_HEADS + h) * NTOT + pos) * HEAD_DIM + lane;
    qO[o] = oq;
    kO[o] = ok;
    vO[o] = xv;
  }
}

// ---------------------------------------------------------------------------
// Flash attention (non-causal), fp32. Block: 64 q-rows, 256 threads.
// Tiles of 64 keys; online softmax; O accumulated in registers (4x4/thread).
// Writes x (B, NTOT, H*64).
// ---------------------------------------------------------------------------
#define LDA 68   // padded stride, multiple of 4

__global__ __launch_bounds__(256) void attn_kernel(
    const float* __restrict__ Qg, const float* __restrict__ Kg,
    const float* __restrict__ Vg, float* __restrict__ xout)
{
  const int qt = blockIdx.x, h = blockIdx.y, b = blockIdx.z;
  const int tid = threadIdx.x, tx = tid & 15, ty = tid >> 4;
  const size_t bh = ((size_t)b * N_HEADS + h) * (size_t)NTOT * HEAD_DIM;

  __shared__ float QsT[64][LDA];   // [d][row]
  __shared__ float KsT[64][LDA];   // [d][col]
  __shared__ float Vs[64][LDA];    // [c][d]
  __shared__ float Ss[64][LDA];    // [row][col] -> P
  __shared__ float m_run[64], l_run[64], fac[64], mnew[64];
  __shared__ float red[64][4];

  const float* Q = Qg + bh + (size_t)qt * 64 * HEAD_DIM;
#pragma unroll
  for (int l = 0; l < 4; ++l) {
    int idx = tid + l * 256;
    int row = idx >> 4;
    int cv = (idx & 15) << 2;
    float4 a = *(const float4*)(Q + row * HEAD_DIM + cv);
    QsT[cv + 0][row] = a.x; QsT[cv + 1][row] = a.y;
    QsT[cv + 2][row] = a.z; QsT[cv + 3][row] = a.w;
  }
  if (tid < 64) { m_run[tid] = -1e30f; l_run[tid] = 0.0f; }

  float o[4][4] = {};
  const float scale = 0.125f;   // 1/sqrt(64)

  for (int kt = 0; kt < NTOT / 64; ++kt) {
    __syncthreads();   // protects Q/m_run init, and prev PV reads of Ks/Vs/Ss
    const float* Kp = Kg + bh + (size_t)kt * 64 * HEAD_DIM;
    const float* Vp = Vg + bh + (size_t)kt * 64 * HEAD_DIM;
#pragma unroll
    for (int l = 0; l < 4; ++l) {
      int idx = tid + l * 256;
      int row = idx >> 4;
      int cv = (idx & 15) << 2;
      float4 a = *(const float4*)(Kp + row * HEAD_DIM + cv);
      KsT[cv + 0][row] = a.x; KsT[cv + 1][row] = a.y;
      KsT[cv + 2][row] = a.z; KsT[cv + 3][row] = a.w;
      float4 v = *(const float4*)(Vp + row * HEAD_DIM + cv);
      *(float4*)&Vs[row][cv] = v;
    }
    __syncthreads();

    // S = scale * Q K^T   (rows ty*4.., cols tx*4..)
    float s[4][4] = {};
    for (int d = 0; d < 64; ++d) {
      float a[4], bb[4];
      *(float4*)a = *(const float4*)&QsT[d][ty * 4];
      *(float4*)bb = *(const float4*)&KsT[d][tx * 4];
#pragma unroll
      for (int i = 0; i < 4; ++i)
#pragma unroll
        for (int j = 0; j < 4; ++j) s[i][j] += a[i] * bb[j];
    }
#pragma unroll
    for (int i = 0; i < 4; ++i) {
      float4 w;
      w.x = s[i][0] * scale; w.y = s[i][1] * scale;
      w.z = s[i][2] * scale; w.w = s[i][3] * scale;
      *(float4*)&Ss[ty * 4 + i][tx * 4] = w;
    }
    __syncthreads();

    // partial row max
    {
      int row = tid >> 2, part = tid & 3;
      float pm = -1e30f;
      for (int c = 0; c < 16; ++c) pm = fmaxf(pm, Ss[row][part * 16 + c]);
      red[row][part] = pm;
    }
    __syncthreads();
    if (tid < 64) {
      float mt = fmaxf(fmaxf(red[tid][0], red[tid][1]),
                       fmaxf(red[tid][2], red[tid][3]));
      float mo = m_run[tid];
      float mn = fmaxf(mo, mt);
      fac[tid] = __expf(mo - mn);
      mnew[tid] = mn;
      m_run[tid] = mn;
    }
    __syncthreads();

    // P = exp(S - mnew) (stored back to Ss), partial sums; rescale O
    {
      int row = tid >> 2, part = tid & 3;
      float mn = mnew[row];
      float psum = 0.0f;
      for (int c = 0; c < 16; ++c) {
        float p = __expf(Ss[row][part * 16 + c] - mn);
        Ss[row][part * 16 + c] = p;
        psum += p;
      }
      red[row][part] = psum;
    }
#pragma unroll
    for (int i = 0; i < 4; ++i) {
      float f = fac[ty * 4 + i];
#pragma unroll
      for (int j = 0; j < 4; ++j) o[i][j] *= f;
    }
    __syncthreads();
    if (tid < 64) {
      l_run[tid] = l_run[tid] * fac[tid]
                 + red[tid][0] + red[tid][1] + red[tid][2] + red[tid][3];
    }

    // O += P @ V
    for (int c = 0; c < 64; ++c) {
      float p[4];
#pragma unroll
      for (int i = 0; i < 4; ++i) p[i] = Ss[ty * 4 + i][c];
      float4 vv = *(const float4*)&Vs[c][tx * 4];
#pragma unroll
      for (int i = 0; i < 4; ++i) {
        o[i][0] += p[i] * vv.x;
        o[i][1] += p[i] * vv.y;
        o[i][2] += p[i] * vv.z;
        o[i][3] += p[i] * vv.w;
      }
    }
  }
  __syncthreads();   // make final l_run visible

  const int n0 = qt * 64;
#pragma unroll
  for (int i = 0; i < 4; ++i) {
    int r = ty * 4 + i;
    float inv = 1.0f / l_run[r];
    float4 w;
    w.x = o[i][0] * inv; w.y = o[i][1] * inv;
    w.z = o[i][2] * inv; w.w = o[i][3] * inv;
    *(float4*)(xout + ((size_t)(b * NTOT + n0 + r)) * D_MODEL
               + h * HEAD_DIM + tx * 4) = w;
  }
}

// ---------------------------------------------------------------------------
extern "C" void kernel_launch(void* const* d_in, const int* in_sizes, int n_in,
                              void* d_out, int out_size, void* d_ws,
                              size_t ws_size, hipStream_t stream)
{
  (void)in_sizes; (void)n_in; (void)out_size; (void)ws_size;

  const float* x1  = (const float*)d_in[0];
  const float* x2  = (const float*)d_in[1];
  const float* Wq1 = (const float*)d_in[2];
  const float* bq1 = (const float*)d_in[3];
  const float* Wq2 = (const float*)d_in[4];
  const float* bq2 = (const float*)d_in[5];
  const float* Wo1 = (const float*)d_in[6];
  const float* bo1 = (const float*)d_in[7];
  const float* Wo2 = (const float*)d_in[8];
  const float* bo2 = (const float*)d_in[9];
  const float* qs1 = (const float*)d_in[10];
  const float* ks1 = (const float*)d_in[11];
  const float* qs2 = (const float*)d_in[12];
  const float* ks2 = (const float*)d_in[13];
  float* out = (float*)d_out;

  float* ws = (float*)d_ws;
  float* qkv1 = ws;                                         // 3072*3072
  float* qkv2 = qkv1 + (size_t)BATCH * SEQ1 * 3 * D_MODEL;  // 1024*3072
  const size_t QKVE = (size_t)BATCH * N_HEADS * NTOT * HEAD_DIM;  // 4.19M
  float* qb = qkv2 + (size_t)BATCH * SEQ2 * 3 * D_MODEL;
  float* kb = qb + QKVE;
  float* vb = kb + QKVE;
  float* xb = qkv1;   // alias: qkv1 dead after transform

  // QKV projections
  gemm_bias<<<dim3(3 * D_MODEL / BN, BATCH * SEQ1 / BM), 256, 0, stream>>>(
      x1, Wq1, bq1, qkv1, BATCH * SEQ1, 3 * D_MODEL, D_MODEL);
  gemm_bias<<<dim3(3 * D_MODEL / BN, BATCH * SEQ2 / BM), 256, 0, stream>>>(
      x2, Wq2, bq2, qkv2, BATCH * SEQ2, 3 * D_MODEL, D_MODEL);

  // RMSNorm + RoPE + scatter
  qkv_transform<<<BATCH * (SEQ1 + SEQ2), 256, 0, stream>>>(
      qkv1, qkv2, qs1, ks1, qs2, ks2, qb, kb, vb);

  // attention
  attn_kernel<<<dim3(NTOT / 64, N_HEADS, BATCH), 256, 0, stream>>>(
      qb, kb, vb, xb);

  // output projections (row ranges are 128-row tile aligned)
  float* out2 = out + (size_t)BATCH * SEQ1 * D_MODEL;
  gemm_bias<<<dim3(D_MODEL / BN, SEQ1 / BM), 256, 0, stream>>>(
      xb, Wo1, bo1, out, SEQ1, D_MODEL, D_MODEL);
  gemm_bias<<<dim3(D_MODEL / BN, SEQ1 / BM), 256, 0, stream>>>(
      xb + (size_t)NTOT * D_MODEL, Wo1, bo1, out + (size_t)SEQ1 * D_MODEL,
      SEQ1, D_MODEL, D_MODEL);
  gemm_bias<<<dim3(D_MODEL / BN, SEQ2 / BM), 256, 0, stream>>>(
      xb + (size_t)SEQ1 * D_MODEL, Wo2, bo2, out2, SEQ2, D_MODEL, D_MODEL);
  gemm_bias<<<dim3(D_MODEL / BN, SEQ2 / BM), 256, 0, stream>>>(
      xb + (size_t)(NTOT + SEQ1) * D_MODEL, Wo2, bo2,
      out2 + (size_t)SEQ2 * D_MODEL, SEQ2, D_MODEL, D_MODEL);
}

// Round 3
// 406.002 us; speedup vs baseline: 3.7063x; 3.7063x over previous
//
#include <hip/hip_runtime.h>
#include <hip/hip_bf16.h>
#include <math.h>

#define D_MODEL 1024
#define N_HEADS 16
#define HEAD_DIM 64
#define SEQ1 1536
#define SEQ2 512
#define NTOT 2048
#define BATCH 2

typedef __attribute__((ext_vector_type(8))) short bf16x8;   // 8 bf16 = 4 VGPR
typedef __attribute__((ext_vector_type(4))) float f32x4;

__device__ __forceinline__ unsigned short f2bf(float f) {
  unsigned u = __builtin_bit_cast(unsigned, f);
  u += 0x7FFFu + ((u >> 16) & 1u);          // RNE
  return (unsigned short)(u >> 16);
}
__device__ __forceinline__ float bf2f(unsigned short h) {
  unsigned u = ((unsigned)h) << 16;
  return __builtin_bit_cast(float, u);
}

// ---------------------------------------------------------------------------
// fp32 -> bf16 conversion (n multiple of 4)
// ---------------------------------------------------------------------------
__global__ __launch_bounds__(256) void cvt_bf16(
    const float* __restrict__ in, unsigned short* __restrict__ out, int n)
{
  int i = (blockIdx.x * 256 + threadIdx.x) * 4;
  if (i < n) {
    float4 v = *(const float4*)(in + i);
    ushort4 o;
    o.x = f2bf(v.x); o.y = f2bf(v.y); o.z = f2bf(v.z); o.w = f2bf(v.w);
    *(ushort4*)(out + i) = o;
  }
}

// ---------------------------------------------------------------------------
// bf16 MFMA GEMM: C[M,N] = A[M,K] @ W[N,K]^T + bias[N]
// 128x128 tile, BK=64, 4 waves (2x2), each wave 64x64 (4x4 MFMA 16x16x32).
// LDS XOR-swizzled (byte ^= (row&7)<<4) => conflict-free ds_read_b128.
// WRITE_BF16: store C as bf16 (ushort) instead of f32.
// ---------------------------------------------------------------------------
template <int WRITE_BF16>
__global__ __launch_bounds__(256) void gemm_bf16(
    const unsigned short* __restrict__ A, const unsigned short* __restrict__ W,
    const float* __restrict__ bias, void* __restrict__ Cv,
    int M, int N, int K)
{
  __shared__ unsigned short Alds[128 * 64];   // 16 KB, swizzled rows of 128B
  __shared__ unsigned short Blds[128 * 64];
  const int tid = threadIdx.x;
  const int lane = tid & 63, wave = tid >> 6;
  const int wm = wave >> 1, wn = wave & 1;
  const int l15 = lane & 15, l4 = lane >> 4;
  const int m0 = blockIdx.y * 128, n0 = blockIdx.x * 128;

  f32x4 acc[4][4];
#pragma unroll
  for (int m = 0; m < 4; ++m)
#pragma unroll
    for (int n = 0; n < 4; ++n)
#pragma unroll
      for (int r = 0; r < 4; ++r) acc[m][n][r] = 0.0f;

  for (int k0 = 0; k0 < K; k0 += 64) {
    __syncthreads();   // prev iter's reads complete before overwrite
#pragma unroll
    for (int c = 0; c < 4; ++c) {
      int off = c * 4096 + tid * 16;              // byte offset in 16KB tile
      int row = off >> 7;                         // 0..127
      int c16 = (off & 127) >> 4;                 // 0..7
      int lo = (row << 7) | ((c16 << 4) ^ ((row & 7) << 4));
      bf16x8 va = *(const bf16x8*)(A + (size_t)(m0 + row) * K + k0 + c16 * 8);
      *(bf16x8*)((char*)Alds + lo) = va;
      bf16x8 vb = *(const bf16x8*)(W + (size_t)(n0 + row) * K + k0 + c16 * 8);
      *(bf16x8*)((char*)Blds + lo) = vb;
    }
    __syncthreads();
#pragma unroll
    for (int kk = 0; kk < 2; ++kk) {
      bf16x8 af[4], bfr[4];
#pragma unroll
      for (int m = 0; m < 4; ++m) {
        int r = wm * 64 + m * 16 + l15;
        int colb = (kk * 64 + l4 * 16) ^ ((r & 7) << 4);
        af[m] = *(const bf16x8*)((const char*)Alds + r * 128 + colb);
      }
#pragma unroll
      for (int n = 0; n < 4; ++n) {
        int r = wn * 64 + n * 16 + l15;
        int colb = (kk * 64 + l4 * 16) ^ ((r & 7) << 4);
        bfr[n] = *(const bf16x8*)((const char*)Blds + r * 128 + colb);
      }
#pragma unroll
      for (int m = 0; m < 4; ++m)
#pragma unroll
        for (int n = 0; n < 4; ++n)
          acc[m][n] = __builtin_amdgcn_mfma_f32_16x16x32_bf16(
              af[m], bfr[n], acc[m][n], 0, 0, 0);
    }
  }

#pragma unroll
  for (int m = 0; m < 4; ++m)
#pragma unroll
    for (int n = 0; n < 4; ++n)
#pragma unroll
      for (int r = 0; r < 4; ++r) {
        int row = m0 + wm * 64 + m * 16 + l4 * 4 + r;
        int col = n0 + wn * 64 + n * 16 + l15;
        float v = acc[m][n][r] + bias[col];
        if (WRITE_BF16)
          ((unsigned short*)Cv)[(size_t)row * N + col] = f2bf(v);
        else
          ((float*)Cv)[(size_t)row * N + col] = v;
      }
}

// ---------------------------------------------------------------------------
// RMSNorm + RoPE on bf16 qkv; writes bf16 q,k,v in (B,H,NTOT,64) layout.
// One block per token row; one wave (=64 lanes = head_dim) per head.
// ---------------------------------------------------------------------------
__global__ __launch_bounds__(256) void qkv_transform(
    const unsigned short* __restrict__ qkv1,
    const unsigned short* __restrict__ qkv2,
    const float* __restrict__ qs1, const float* __restrict__ ks1,
    const float* __restrict__ qs2, const float* __restrict__ ks2,
    unsigned short* __restrict__ qO, unsigned short* __restrict__ kO,
    unsigned short* __restrict__ vO)
{
  const int row = blockIdx.x;                 // 0..4095
  const int lane = threadIdx.x & 63;
  const int wave = threadIdx.x >> 6;

  const unsigned short* src;
  const float* qs;
  const float* ks;
  int b, pos;
  if (row < BATCH * SEQ1) {
    b = row / SEQ1;
    pos = row % SEQ1;
    src = qkv1 + (size_t)row * (3 * D_MODEL);
    qs = qs1; ks = ks1;
  } else {
    int r2 = row - BATCH * SEQ1;
    b = r2 / SEQ2;
    pos = SEQ1 + (r2 % SEQ2);
    src = qkv2 + (size_t)r2 * (3 * D_MODEL);
    qs = qs2; ks = ks2;
  }

  const int j = lane >> 1;
  const float LOG2_THETA = 13.287712379549449f;      // log2(10000)
  float inv_freq = exp2f(-((float)(2 * j) / 64.0f) * LOG2_THETA);
  float ang = (float)pos * inv_freq;
  float sn, cs;
  sincosf(ang, &sn, &cs);

  for (int h = wave; h < N_HEADS; h += 4) {
    float xq = bf2f(src[0 * D_MODEL + h * HEAD_DIM + lane]);
    float xk = bf2f(src[1 * D_MODEL + h * HEAD_DIM + lane]);
    float xv = bf2f(src[2 * D_MODEL + h * HEAD_DIM + lane]);

    float sq = xq * xq, sk = xk * xk;
#pragma unroll
    for (int o = 32; o > 0; o >>= 1) {
      sq += __shfl_xor(sq, o);
      sk += __shfl_xor(sk, o);
    }
    float xqn = xq * rsqrtf(sq * (1.0f / 64.0f) + 1e-6f) * qs[lane];
    float xkn = xk * rsqrtf(sk * (1.0f / 64.0f) + 1e-6f) * ks[lane];

    float pq = __shfl_xor(xqn, 1);
    float pk = __shfl_xor(xkn, 1);
    float oq, ok;
    if (lane & 1) { oq = pq * sn + xqn * cs; ok = pk * sn + xkn * cs; }
    else          { oq = xqn * cs - pq * sn; ok = xkn * cs - pk * sn; }

    size_t o = (((size_t)b * N_HEADS + h) * NTOT + pos) * HEAD_DIM + lane;
    qO[o] = f2bf(oq);
    kO[o] = f2bf(ok);
    vO[o] = f2bf(xv);
  }
}

// ---------------------------------------------------------------------------
// V transpose: (BH, NTOT, 64) -> (BH, 64, NTOT), bf16, 64x64 tiles.
// ---------------------------------------------------------------------------
__global__ __launch_bounds__(256) void v_transpose(
    const unsigned short* __restrict__ v, unsigned short* __restrict__ vt)
{
  const int pt = blockIdx.x, bh = blockIdx.y;
  __shared__ unsigned short t[64][72];          // padded
  const int tid = threadIdx.x;
  const unsigned short* src = v + ((size_t)bh * NTOT + pt * 64) * 64;
#pragma unroll
  for (int c = 0; c < 2; ++c) {
    int off = c * 4096 + tid * 16;
    int row = off >> 7, c16 = (off & 127) >> 4;
    bf16x8 x = *(const bf16x8*)(src + row * 64 + c16 * 8);
#pragma unroll
    for (int j = 0; j < 8; ++j) t[row][c16 * 8 + j] = (unsigned short)x[j];
  }
  __syncthreads();
  unsigned short* dst = vt + (size_t)bh * 64 * NTOT + pt * 64;
#pragma unroll
  for (int c = 0; c < 2; ++c) {
    int off = c * 4096 + tid * 16;
    int d = off >> 7, p16 = (off & 127) >> 4;
    bf16x8 x;
#pragma unroll
    for (int j = 0; j < 8; ++j) x[j] = (short)t[p16 * 8 + j][d];
    *(bf16x8*)(dst + (size_t)d * NTOT + p16 * 8) = x;
  }
}

// ---------------------------------------------------------------------------
// MFMA flash attention. Block = 4 waves, 64 q-rows (wave w owns rows w*16..).
// K-tiles of 64. K,VT,P tiles in XOR-swizzled LDS. Softmax in registers.
// Writes bf16 x (B, NTOT, 1024).
// ---------------------------------------------------------------------------
__global__ __launch_bounds__(256) void attn_mfma(
    const unsigned short* __restrict__ Qg, const unsigned short* __restrict__ Kg,
    const unsigned short* __restrict__ VTg, unsigned short* __restrict__ xout)
{
  const int qt = blockIdx.x, bh = blockIdx.y;
  const int b = bh >> 4, h = bh & 15;
  const int tid = threadIdx.x, lane = tid & 63, w = tid >> 6;
  const int l15 = lane & 15, l4 = lane >> 4;

  __shared__ unsigned short Klds[64 * 64];   // [krow][d], swizzled
  __shared__ unsigned short Vlds[64 * 64];   // [d][kc],  swizzled (V^T)
  __shared__ unsigned short Plds[64 * 64];   // [qrow][kc], swizzled

  const size_t base = (size_t)bh * NTOT * HEAD_DIM;
  bf16x8 qf[2];
  {
    const unsigned short* qp =
        Qg + base + (size_t)(qt * 64 + w * 16 + l15) * 64 + l4 * 8;
    qf[0] = *(const bf16x8*)qp;
    qf[1] = *(const bf16x8*)(qp + 32);
  }

  f32x4 acc_o[4];
#pragma unroll
  for (int dt = 0; dt < 4; ++dt)
#pragma unroll
    for (int r = 0; r < 4; ++r) acc_o[dt][r] = 0.0f;
  float m_run[4], l_run[4];
#pragma unroll
  for (int r = 0; r < 4; ++r) { m_run[r] = -1e30f; l_run[r] = 0.0f; }

  const unsigned short* kp = Kg + base;
  const unsigned short* vtp = VTg + (size_t)bh * HEAD_DIM * NTOT;

  for (int kt = 0; kt < NTOT / 64; ++kt) {
    __syncthreads();
#pragma unroll
    for (int c = 0; c < 2; ++c) {
      int off = c * 4096 + tid * 16;
      int row = off >> 7, c16 = (off & 127) >> 4;
      int lo = (row << 7) | ((c16 << 4) ^ ((row & 7) << 4));
      bf16x8 kv = *(const bf16x8*)(kp + (size_t)(kt * 64 + row) * 64 + c16 * 8);
      *(bf16x8*)((char*)Klds + lo) = kv;
      bf16x8 vv = *(const bf16x8*)(vtp + (size_t)row * NTOT + kt * 64 + c16 * 8);
      *(bf16x8*)((char*)Vlds + lo) = vv;
    }
    __syncthreads();

    // S = Q K^T (wave w: q-rows w*16..w*16+15, all 64 k-cols)
    f32x4 sacc[4];
#pragma unroll
    for (int ct = 0; ct < 4; ++ct)
#pragma unroll
      for (int r = 0; r < 4; ++r) sacc[ct][r] = 0.0f;
#pragma unroll
    for (int kk = 0; kk < 2; ++kk) {
#pragma unroll
      for (int ct = 0; ct < 4; ++ct) {
        int r = ct * 16 + l15;
        int colb = (kk * 64 + l4 * 16) ^ ((r & 7) << 4);
        bf16x8 kf = *(const bf16x8*)((const char*)Klds + r * 128 + colb);
        sacc[ct] = __builtin_amdgcn_mfma_f32_16x16x32_bf16(
            qf[kk], kf, sacc[ct], 0, 0, 0);
      }
    }

    // online softmax (rows = w*16 + l4*4 + r; cols spread over l15 x 4 tiles)
    float p[4][4], fac[4];
#pragma unroll
    for (int r = 0; r < 4; ++r) {
      float tm = -1e30f;
#pragma unroll
      for (int ct = 0; ct < 4; ++ct) {
        float s = sacc[ct][r] * 0.125f;
        p[ct][r] = s;
        tm = fmaxf(tm, s);
      }
#pragma unroll
      for (int o = 1; o < 16; o <<= 1) tm = fmaxf(tm, __shfl_xor(tm, o));
      float mn = fmaxf(m_run[r], tm);
      fac[r] = __expf(m_run[r] - mn);
      m_run[r] = mn;
      float rs = 0.0f;
#pragma unroll
      for (int ct = 0; ct < 4; ++ct) {
        float pv = __expf(p[ct][r] - mn);
        p[ct][r] = pv;
        rs += pv;
      }
#pragma unroll
      for (int o = 1; o < 16; o <<= 1) rs += __shfl_xor(rs, o);
      l_run[r] = l_run[r] * fac[r] + rs;
    }
#pragma unroll
    for (int dt = 0; dt < 4; ++dt)
#pragma unroll
      for (int r = 0; r < 4; ++r) acc_o[dt][r] *= fac[r];

    // write P (bf16) to swizzled LDS
#pragma unroll
    for (int ct = 0; ct < 4; ++ct)
#pragma unroll
      for (int r = 0; r < 4; ++r) {
        int row = w * 16 + l4 * 4 + r;
        int colb = (ct * 32 + l15 * 2) ^ ((row & 7) << 4);
        *(unsigned short*)((char*)Plds + row * 128 + colb) = f2bf(p[ct][r]);
      }
    __syncthreads();

    // O += P @ V
#pragma unroll
    for (int ks = 0; ks < 2; ++ks) {
      int pr = w * 16 + l15;
      int pcolb = (ks * 64 + l4 * 16) ^ ((pr & 7) << 4);
      bf16x8 pf = *(const bf16x8*)((const char*)Plds + pr * 128 + pcolb);
#pragma unroll
      for (int dt = 0; dt < 4; ++dt) {
        int vr = dt * 16 + l15;
        int vcolb = (ks * 64 + l4 * 16) ^ ((vr & 7) << 4);
        bf16x8 vf = *(const bf16x8*)((const char*)Vlds + vr * 128 + vcolb);
        acc_o[dt] = __builtin_amdgcn_mfma_f32_16x16x32_bf16(
            pf, vf, acc_o[dt], 0, 0, 0);
      }
    }
  }

#pragma unroll
  for (int dt = 0; dt < 4; ++dt)
#pragma unroll
    for (int r = 0; r < 4; ++r) {
      int row = qt * 64 + w * 16 + l4 * 4 + r;
      int col = h * 64 + dt * 16 + l15;
      float v = acc_o[dt][r] / l_run[r];
      xout[(size_t)(b * NTOT + row) * D_MODEL + col] = f2bf(v);
    }
}

// ---------------------------------------------------------------------------
extern "C" void kernel_launch(void* const* d_in, const int* in_sizes, int n_in,
                              void* d_out, int out_size, void* d_ws,
                              size_t ws_size, hipStream_t stream)
{
  (void)in_sizes; (void)n_in; (void)out_size; (void)ws_size;

  const float* x1  = (const float*)d_in[0];
  const float* x2  = (const float*)d_in[1];
  const float* Wq1 = (const float*)d_in[2];
  const float* bq1 = (const float*)d_in[3];
  const float* Wq2 = (const float*)d_in[4];
  const float* bq2 = (const float*)d_in[5];
  const float* Wo1 = (const float*)d_in[6];
  const float* bo1 = (const float*)d_in[7];
  const float* Wo2 = (const float*)d_in[8];
  const float* bo2 = (const float*)d_in[9];
  const float* qs1 = (const float*)d_in[10];
  const float* ks1 = (const float*)d_in[11];
  const float* qs2 = (const float*)d_in[12];
  const float* ks2 = (const float*)d_in[13];
  float* out = (float*)d_out;

  unsigned short* ws = (unsigned short*)d_ws;
  const size_t SX1 = (size_t)BATCH * SEQ1 * D_MODEL;      // 3.146M
  const size_t SX2 = (size_t)BATCH * SEQ2 * D_MODEL;      // 1.049M
  const size_t SW  = (size_t)3 * D_MODEL * D_MODEL;       // 3.146M
  const size_t SWO = (size_t)D_MODEL * D_MODEL;           // 1.049M
  const size_t SQ1 = (size_t)BATCH * SEQ1 * 3 * D_MODEL;  // 9.437M
  const size_t SQ2 = (size_t)BATCH * SEQ2 * 3 * D_MODEL;  // 3.146M
  const size_t SH  = (size_t)BATCH * N_HEADS * NTOT * HEAD_DIM;  // 4.194M

  unsigned short* x1b  = ws;
  unsigned short* x2b  = x1b + SX1;
  unsigned short* Wq1b = x2b + SX2;
  unsigned short* Wq2b = Wq1b + SW;
  unsigned short* Wo1b = Wq2b + SW;
  unsigned short* Wo2b = Wo1b + SWO;
  unsigned short* qkv1 = Wo2b + SWO;
  unsigned short* qkv2 = qkv1 + SQ1;
  unsigned short* qb   = qkv2 + SQ2;
  unsigned short* kb   = qb + SH;
  unsigned short* vb   = kb + SH;
  unsigned short* vtb  = vb + SH;
  unsigned short* xb   = vtb + SH;   // bf16 attn output (B,NTOT,1024)

  // fp32 -> bf16 conversions
  cvt_bf16<<<SX1 / 1024, 256, 0, stream>>>(x1, x1b, (int)SX1);
  cvt_bf16<<<SX2 / 1024, 256, 0, stream>>>(x2, x2b, (int)SX2);
  cvt_bf16<<<SW / 1024, 256, 0, stream>>>(Wq1, Wq1b, (int)SW);
  cvt_bf16<<<SW / 1024, 256, 0, stream>>>(Wq2, Wq2b, (int)SW);
  cvt_bf16<<<SWO / 1024, 256, 0, stream>>>(Wo1, Wo1b, (int)SWO);
  cvt_bf16<<<SWO / 1024, 256, 0, stream>>>(Wo2, Wo2b, (int)SWO);

  // QKV projections (bf16 out)
  gemm_bf16<1><<<dim3(3 * D_MODEL / 128, BATCH * SEQ1 / 128), 256, 0, stream>>>(
      x1b, Wq1b, bq1, qkv1, BATCH * SEQ1, 3 * D_MODEL, D_MODEL);
  gemm_bf16<1><<<dim3(3 * D_MODEL / 128, BATCH * SEQ2 / 128), 256, 0, stream>>>(
      x2b, Wq2b, bq2, qkv2, BATCH * SEQ2, 3 * D_MODEL, D_MODEL);

  // RMSNorm + RoPE + scatter (bf16)
  qkv_transform<<<BATCH * (SEQ1 + SEQ2), 256, 0, stream>>>(
      qkv1, qkv2, qs1, ks1, qs2, ks2, qb, kb, vb);

  // V transpose for PV operand
  v_transpose<<<dim3(NTOT / 64, BATCH * N_HEADS), 256, 0, stream>>>(vb, vtb);

  // attention
  attn_mfma<<<dim3(NTOT / 64, BATCH * N_HEADS), 256, 0, stream>>>(
      qb, kb, vtb, xb);

  // output projections (f32 out)
  float* out2 = out + (size_t)BATCH * SEQ1 * D_MODEL;
  gemm_bf16<0><<<dim3(D_MODEL / 128, SEQ1 / 128), 256, 0, stream>>>(
      xb, Wo1b, bo1, out, SEQ1, D_MODEL, D_MODEL);
  gemm_bf16<0><<<dim3(D_MODEL / 128, SEQ1 / 128), 256, 0, stream>>>(
      xb + (size_t)NTOT * D_MODEL, Wo1b, bo1, out + (size_t)SEQ1 * D_MODEL,
      SEQ1, D_MODEL, D_MODEL);
  gemm_bf16<0><<<dim3(D_MODEL / 128, SEQ2 / 128), 256, 0, stream>>>(
      xb + (size_t)SEQ1 * D_MODEL, Wo2b, bo2, out2, SEQ2, D_MODEL, D_MODEL);
  gemm_bf16<0><<<dim3(D_MODEL / 128, SEQ2 / 128), 256, 0, stream>>>(
      xb + (size_t)(NTOT + SEQ1) * D_MODEL, Wo2b, bo2,
      out2 + (size_t)SEQ2 * D_MODEL, SEQ2, D_MODEL, D_MODEL);
}

// Round 4
// 348.194 us; speedup vs baseline: 4.3216x; 1.1660x over previous
//
#include <hip/hip_runtime.h>
#include <hip/hip_bf16.h>
#include <math.h>

#define D_MODEL 1024
#define N_HEADS 16
#define HEAD_DIM 64
#define SEQ1 1536
#define SEQ2 512
#define NTOT 2048
#define BATCH 2

typedef __attribute__((ext_vector_type(8))) short bf16x8;   // 8 bf16 = 4 VGPR
typedef __attribute__((ext_vector_type(4))) float f32x4;

__device__ __forceinline__ unsigned short f2bf(float f) {
  unsigned u = __builtin_bit_cast(unsigned, f);
  u += 0x7FFFu + ((u >> 16) & 1u);          // RNE
  return (unsigned short)(u >> 16);
}
__device__ __forceinline__ float bf2f(unsigned short h) {
  unsigned u = ((unsigned)h) << 16;
  return __builtin_bit_cast(float, u);
}

// async global->LDS, 16B per lane. dst must be wave-uniform; HW writes
// dst + lane*16. Swizzling is done on the SOURCE address (m173 pattern).
__device__ __forceinline__ void gload16(const void* g, void* l) {
  __builtin_amdgcn_global_load_lds(
      (const __attribute__((address_space(1))) void*)g,
      (__attribute__((address_space(3))) void*)l, 16, 0, 0);
}

// ---------------------------------------------------------------------------
// Single fused fp32 -> bf16 conversion over 6 segments.
// ---------------------------------------------------------------------------
struct CvtArgs {
  const float* src[6];
  unsigned short* dst[6];
  int prefix[7];   // element prefix sums, all multiples of 4
};

__global__ __launch_bounds__(256) void cvt_all(CvtArgs a)
{
  int e = (blockIdx.x * 256 + threadIdx.x) * 4;
  if (e >= a.prefix[6]) return;
  int s = 0;
#pragma unroll
  for (int i = 1; i < 6; ++i) s += (e >= a.prefix[i]) ? 1 : 0;
  int lo = e - a.prefix[s];
  float4 v = *(const float4*)(a.src[s] + lo);
  ushort4 o;
  o.x = f2bf(v.x); o.y = f2bf(v.y); o.z = f2bf(v.z); o.w = f2bf(v.w);
  *(ushort4*)(a.dst[s] + lo) = o;
}

// ---------------------------------------------------------------------------
// bf16 MFMA GEMM: C[M,N] = A[M,K] @ W[N,K]^T + bias[N]
// 128x128 tile, BK=64, 4 waves (2x2), each wave 64x64 (4x4 MFMA 16x16x32).
// Staging via global_load_lds w=16: LDS dest linear, global source chunk
// pre-swizzled (c16 ^= row&7); ds_read applies the same XOR. Conflict-free.
// ---------------------------------------------------------------------------
template <int WRITE_BF16>
__global__ __launch_bounds__(256) void gemm_bf16(
    const unsigned short* __restrict__ A, const unsigned short* __restrict__ W,
    const float* __restrict__ bias, void* __restrict__ Cv,
    int M, int N, int K)
{
  __shared__ __align__(16) unsigned short Alds[128 * 64];   // 16 KB
  __shared__ __align__(16) unsigned short Blds[128 * 64];
  const int tid = threadIdx.x;
  const int lane = tid & 63, wave = tid >> 6;
  const int wm = wave >> 1, wn = wave & 1;
  const int l15 = lane & 15, l4 = lane >> 4;
  const int m0 = blockIdx.y * 128, n0 = blockIdx.x * 128;

  f32x4 acc[4][4];
#pragma unroll
  for (int m = 0; m < 4; ++m)
#pragma unroll
    for (int n = 0; n < 4; ++n)
#pragma unroll
      for (int r = 0; r < 4; ++r) acc[m][n][r] = 0.0f;

  for (int k0 = 0; k0 < K; k0 += 64) {
    __syncthreads();   // prev iter's reads complete before overwrite
#pragma unroll
    for (int c = 0; c < 4; ++c) {
      int off = c * 4096 + tid * 16;              // linear LDS byte offset
      int row = off >> 7;                         // 0..127
      int c16g = ((off & 127) >> 4) ^ (row & 7);  // pre-swizzled global chunk
      int dstb = c * 4096 + (tid >> 6) * 1024;    // wave-uniform dest
      gload16(A + (size_t)(m0 + row) * K + k0 + c16g * 8, (char*)Alds + dstb);
      gload16(W + (size_t)(n0 + row) * K + k0 + c16g * 8, (char*)Blds + dstb);
    }
    __syncthreads();   // drains vmcnt before barrier
#pragma unroll
    for (int kk = 0; kk < 2; ++kk) {
      bf16x8 af[4], bfr[4];
#pragma unroll
      for (int m = 0; m < 4; ++m) {
        int r = wm * 64 + m * 16 + l15;
        int colb = (kk * 64 + l4 * 16) ^ ((r & 7) << 4);
        af[m] = *(const bf16x8*)((const char*)Alds + r * 128 + colb);
      }
#pragma unroll
      for (int n = 0; n < 4; ++n) {
        int r = wn * 64 + n * 16 + l15;
        int colb = (kk * 64 + l4 * 16) ^ ((r & 7) << 4);
        bfr[n] = *(const bf16x8*)((const char*)Blds + r * 128 + colb);
      }
#pragma unroll
      for (int m = 0; m < 4; ++m)
#pragma unroll
        for (int n = 0; n < 4; ++n)
          acc[m][n] = __builtin_amdgcn_mfma_f32_16x16x32_bf16(
              af[m], bfr[n], acc[m][n], 0, 0, 0);
    }
  }

#pragma unroll
  for (int m = 0; m < 4; ++m)
#pragma unroll
    for (int n = 0; n < 4; ++n)
#pragma unroll
      for (int r = 0; r < 4; ++r) {
        int row = m0 + wm * 64 + m * 16 + l4 * 4 + r;
        int col = n0 + wn * 64 + n * 16 + l15;
        float v = acc[m][n][r] + bias[col];
        if (WRITE_BF16)
          ((unsigned short*)Cv)[(size_t)row * N + col] = f2bf(v);
        else
          ((float*)Cv)[(size_t)row * N + col] = v;
      }
}

// ---------------------------------------------------------------------------
// RMSNorm + RoPE on bf16 qkv; q pre-scaled by 0.125*log2(e) for the
// exp2-domain softmax. Writes bf16 q,k,v in (B,H,NTOT,64).
// ---------------------------------------------------------------------------
__global__ __launch_bounds__(256) void qkv_transform(
    const unsigned short* __restrict__ qkv1,
    const unsigned short* __restrict__ qkv2,
    const float* __restrict__ qs1, const float* __restrict__ ks1,
    const float* __restrict__ qs2, const float* __restrict__ ks2,
    unsigned short* __restrict__ qO, unsigned short* __restrict__ kO,
    unsigned short* __restrict__ vO)
{
  const int row = blockIdx.x;                 // 0..4095
  const int lane = threadIdx.x & 63;
  const int wave = threadIdx.x >> 6;
  const float QSCALE = 0.18033688011112042f;  // 0.125 * log2(e)

  const unsigned short* src;
  const float* qs;
  const float* ks;
  int b, pos;
  if (row < BATCH * SEQ1) {
    b = row / SEQ1;
    pos = row % SEQ1;
    src = qkv1 + (size_t)row * (3 * D_MODEL);
    qs = qs1; ks = ks1;
  } else {
    int r2 = row - BATCH * SEQ1;
    b = r2 / SEQ2;
    pos = SEQ1 + (r2 % SEQ2);
    src = qkv2 + (size_t)r2 * (3 * D_MODEL);
    qs = qs2; ks = ks2;
  }

  const int j = lane >> 1;
  const float LOG2_THETA = 13.287712379549449f;      // log2(10000)
  float inv_freq = exp2f(-((float)(2 * j) / 64.0f) * LOG2_THETA);
  float ang = (float)pos * inv_freq;
  float sn, cs;
  sincosf(ang, &sn, &cs);

  for (int h = wave; h < N_HEADS; h += 4) {
    float xq = bf2f(src[0 * D_MODEL + h * HEAD_DIM + lane]);
    float xk = bf2f(src[1 * D_MODEL + h * HEAD_DIM + lane]);
    float xv = bf2f(src[2 * D_MODEL + h * HEAD_DIM + lane]);

    float sq = xq * xq, sk = xk * xk;
#pragma unroll
    for (int o = 32; o > 0; o >>= 1) {
      sq += __shfl_xor(sq, o);
      sk += __shfl_xor(sk, o);
    }
    float xqn = xq * rsqrtf(sq * (1.0f / 64.0f) + 1e-6f) * qs[lane];
    float xkn = xk * rsqrtf(sk * (1.0f / 64.0f) + 1e-6f) * ks[lane];

    float pq = __shfl_xor(xqn, 1);
    float pk = __shfl_xor(xkn, 1);
    float oq, ok;
    if (lane & 1) { oq = pq * sn + xqn * cs; ok = pk * sn + xkn * cs; }
    else          { oq = xqn * cs - pq * sn; ok = xkn * cs - pk * sn; }

    size_t o = (((size_t)b * N_HEADS + h) * NTOT + pos) * HEAD_DIM + lane;
    qO[o] = f2bf(oq * QSCALE);
    kO[o] = f2bf(ok);
    vO[o] = f2bf(xv);
  }
}

// ---------------------------------------------------------------------------
// V transpose: (BH, NTOT, 64) -> (BH, 64, NTOT), bf16, 64x64 tiles.
// ---------------------------------------------------------------------------
__global__ __launch_bounds__(256) void v_transpose(
    const unsigned short* __restrict__ v, unsigned short* __restrict__ vt)
{
  const int pt = blockIdx.x, bh = blockIdx.y;
  __shared__ unsigned short t[64][72];          // padded
  const int tid = threadIdx.x;
  const unsigned short* src = v + ((size_t)bh * NTOT + pt * 64) * 64;
#pragma unroll
  for (int c = 0; c < 2; ++c) {
    int off = c * 4096 + tid * 16;
    int row = off >> 7, c16 = (off & 127) >> 4;
    bf16x8 x = *(const bf16x8*)(src + row * 64 + c16 * 8);
#pragma unroll
    for (int j = 0; j < 8; ++j) t[row][c16 * 8 + j] = (unsigned short)x[j];
  }
  __syncthreads();
  unsigned short* dst = vt + (size_t)bh * 64 * NTOT + pt * 64;
#pragma unroll
  for (int c = 0; c < 2; ++c) {
    int off = c * 4096 + tid * 16;
    int d = off >> 7, p16 = (off & 127) >> 4;
    bf16x8 x;
#pragma unroll
    for (int j = 0; j < 8; ++j) x[j] = (short)t[p16 * 8 + j][d];
    *(bf16x8*)(dst + (size_t)d * NTOT + p16 * 8) = x;
  }
}

// ---------------------------------------------------------------------------
// MFMA flash attention. QBLK=128 (4 waves x 2 row-groups of 16), KVBLK=64.
// exp2-domain softmax (scale*log2e folded into Q), row-sum via ones-MFMA,
// defer-max (THR=8). Writes bf16 rows split into xb1 (seq1) / xb2 (seq2).
// ---------------------------------------------------------------------------
__global__ __launch_bounds__(256) void attn_mfma(
    const unsigned short* __restrict__ Qg, const unsigned short* __restrict__ Kg,
    const unsigned short* __restrict__ VTg,
    unsigned short* __restrict__ xb1, unsigned short* __restrict__ xb2)
{
  const int qt = blockIdx.x, bh = blockIdx.y;
  const int b = bh >> 4, h = bh & 15;
  const int tid = threadIdx.x, lane = tid & 63, w = tid >> 6;
  const int l15 = lane & 15, l4 = lane >> 4;

  __shared__ __align__(16) unsigned short Klds[64 * 64];    // [k][d] swz
  __shared__ __align__(16) unsigned short Vlds[64 * 64];    // [d][kc] swz
  __shared__ __align__(16) unsigned short Plds[128 * 64];   // [q][kc] swz

  const size_t base = (size_t)bh * NTOT * HEAD_DIM;
  bf16x8 qf[2][2];
#pragma unroll
  for (int g = 0; g < 2; ++g) {
    const unsigned short* qp =
        Qg + base + (size_t)(qt * 128 + g * 64 + w * 16 + l15) * 64 + l4 * 8;
    qf[g][0] = *(const bf16x8*)qp;
    qf[g][1] = *(const bf16x8*)(qp + 32);
  }

  bf16x8 ones;
#pragma unroll
  for (int i = 0; i < 8; ++i) ones[i] = (short)0x3F80;   // bf16 1.0

  f32x4 acc_o[2][4], acc_l[2];
  float m_run[2][4];
#pragma unroll
  for (int g = 0; g < 2; ++g) {
#pragma unroll
    for (int dt = 0; dt < 4; ++dt)
#pragma unroll
      for (int r = 0; r < 4; ++r) acc_o[g][dt][r] = 0.0f;
#pragma unroll
    for (int r = 0; r < 4; ++r) { acc_l[g][r] = 0.0f; m_run[g][r] = -1e30f; }
  }

  const unsigned short* kp = Kg + base;
  const unsigned short* vtp = VTg + (size_t)bh * HEAD_DIM * NTOT;

  for (int kt = 0; kt < NTOT / 64; ++kt) {
    __syncthreads();
#pragma unroll
    for (int c = 0; c < 2; ++c) {
      int off = c * 4096 + tid * 16;
      int row = off >> 7;                          // 0..63
      int c16g = ((off & 127) >> 4) ^ (row & 7);
      int dstb = c * 4096 + (tid >> 6) * 1024;
      gload16(kp + (size_t)(kt * 64 + row) * 64 + c16g * 8,
              (char*)Klds + dstb);
      gload16(vtp + (size_t)row * NTOT + kt * 64 + c16g * 8,
              (char*)Vlds + dstb);
    }
    __syncthreads();

    // S' = (Q*0.125*log2e) K^T   for both row-groups, sharing K reads
    f32x4 sacc[2][4];
#pragma unroll
    for (int g = 0; g < 2; ++g)
#pragma unroll
      for (int ct = 0; ct < 4; ++ct)
#pragma unroll
        for (int r = 0; r < 4; ++r) sacc[g][ct][r] = 0.0f;
#pragma unroll
    for (int kk = 0; kk < 2; ++kk) {
#pragma unroll
      for (int ct = 0; ct < 4; ++ct) {
        int r = ct * 16 + l15;
        int colb = (kk * 64 + l4 * 16) ^ ((r & 7) << 4);
        bf16x8 kf = *(const bf16x8*)((const char*)Klds + r * 128 + colb);
#pragma unroll
        for (int g = 0; g < 2; ++g)
          sacc[g][ct] = __builtin_amdgcn_mfma_f32_16x16x32_bf16(
              qf[g][kk], kf, sacc[g][ct], 0, 0, 0);
      }
    }

    // online softmax in exp2 domain; P -> swizzled LDS (wave-private rows)
#pragma unroll
    for (int g = 0; g < 2; ++g) {
#pragma unroll
      for (int r = 0; r < 4; ++r) {
        float tm = fmaxf(fmaxf(sacc[g][0][r], sacc[g][1][r]),
                         fmaxf(sacc[g][2][r], sacc[g][3][r]));
#pragma unroll
        for (int o = 1; o < 16; o <<= 1) tm = fmaxf(tm, __shfl_xor(tm, o));
        float mo = m_run[g][r];
        if (tm > mo + 8.0f) {              // rescale path (defer-max)
          float fac = exp2f(mo - tm);
          m_run[g][r] = tm;
#pragma unroll
          for (int dt = 0; dt < 4; ++dt) acc_o[g][dt][r] *= fac;
          acc_l[g][r] *= fac;
        }
        float mc = m_run[g][r];
        int row = g * 64 + w * 16 + l4 * 4 + r;
#pragma unroll
        for (int ct = 0; ct < 4; ++ct) {
          float pv = exp2f(sacc[g][ct][r] - mc);
          int colb = (ct * 32 + l15 * 2) ^ ((row & 7) << 4);
          *(unsigned short*)((char*)Plds + row * 128 + colb) = f2bf(pv);
        }
      }
    }
    // no barrier: each wave reads only its own P rows

    // O += P @ V ; l += P @ 1   (V reads shared across row-groups)
#pragma unroll
    for (int ks = 0; ks < 2; ++ks) {
      bf16x8 pf[2];
#pragma unroll
      for (int g = 0; g < 2; ++g) {
        int pr = g * 64 + w * 16 + l15;
        int pcolb = (ks * 64 + l4 * 16) ^ ((pr & 7) << 4);
        pf[g] = *(const bf16x8*)((const char*)Plds + pr * 128 + pcolb);
      }
#pragma unroll
      for (int dt = 0; dt < 4; ++dt) {
        int vr = dt * 16 + l15;
        int vcolb = (ks * 64 + l4 * 16) ^ ((vr & 7) << 4);
        bf16x8 vf = *(const bf16x8*)((const char*)Vlds + vr * 128 + vcolb);
#pragma unroll
        for (int g = 0; g < 2; ++g)
          acc_o[g][dt] = __builtin_amdgcn_mfma_f32_16x16x32_bf16(
              pf[g], vf, acc_o[g][dt], 0, 0, 0);
      }
#pragma unroll
      for (int g = 0; g < 2; ++g)
        acc_l[g] = __builtin_amdgcn_mfma_f32_16x16x32_bf16(
            pf[g], ones, acc_l[g], 0, 0, 0);
    }
  }

#pragma unroll
  for (int g = 0; g < 2; ++g)
#pragma unroll
    for (int r = 0; r < 4; ++r) {
      int n = qt * 128 + g * 64 + w * 16 + l4 * 4 + r;
      float inv = 1.0f / acc_l[g][r];
      unsigned short* dst;
      if (n < SEQ1) dst = xb1 + ((size_t)b * SEQ1 + n) * D_MODEL;
      else          dst = xb2 + ((size_t)b * SEQ2 + (n - SEQ1)) * D_MODEL;
#pragma unroll
      for (int dt = 0; dt < 4; ++dt)
        dst[h * 64 + dt * 16 + l15] = f2bf(acc_o[g][dt][r] * inv);
    }
}

// ---------------------------------------------------------------------------
extern "C" void kernel_launch(void* const* d_in, const int* in_sizes, int n_in,
                              void* d_out, int out_size, void* d_ws,
                              size_t ws_size, hipStream_t stream)
{
  (void)in_sizes; (void)n_in; (void)out_size; (void)ws_size;

  const float* x1  = (const float*)d_in[0];
  const float* x2  = (const float*)d_in[1];
  const float* Wq1 = (const float*)d_in[2];
  const float* bq1 = (const float*)d_in[3];
  const float* Wq2 = (const float*)d_in[4];
  const float* bq2 = (const float*)d_in[5];
  const float* Wo1 = (const float*)d_in[6];
  const float* bo1 = (const float*)d_in[7];
  const float* Wo2 = (const float*)d_in[8];
  const float* bo2 = (const float*)d_in[9];
  const float* qs1 = (const float*)d_in[10];
  const float* ks1 = (const float*)d_in[11];
  const float* qs2 = (const float*)d_in[12];
  const float* ks2 = (const float*)d_in[13];
  float* out = (float*)d_out;

  unsigned short* ws = (unsigned short*)d_ws;
  const size_t SX1 = (size_t)BATCH * SEQ1 * D_MODEL;      // 3.146M
  const size_t SX2 = (size_t)BATCH * SEQ2 * D_MODEL;      // 1.049M
  const size_t SW  = (size_t)3 * D_MODEL * D_MODEL;       // 3.146M
  const size_t SWO = (size_t)D_MODEL * D_MODEL;           // 1.049M
  const size_t SQ1 = (size_t)BATCH * SEQ1 * 3 * D_MODEL;  // 9.437M
  const size_t SQ2 = (size_t)BATCH * SEQ2 * 3 * D_MODEL;  // 3.146M
  const size_t SH  = (size_t)BATCH * N_HEADS * NTOT * HEAD_DIM;  // 4.194M

  unsigned short* x1b  = ws;
  unsigned short* x2b  = x1b + SX1;
  unsigned short* Wq1b = x2b + SX2;
  unsigned short* Wq2b = Wq1b + SW;
  unsigned short* Wo1b = Wq2b + SW;
  unsigned short* Wo2b = Wo1b + SWO;
  unsigned short* qkv1 = Wo2b + SWO;
  unsigned short* qkv2 = qkv1 + SQ1;
  unsigned short* qb   = qkv2 + SQ2;
  unsigned short* kb   = qb + SH;
  unsigned short* vb   = kb + SH;
  unsigned short* vtb  = vb + SH;
  unsigned short* xb1  = vtb + SH;          // (B,SEQ1,1024) bf16
  unsigned short* xb2  = xb1 + SX1;         // (B,SEQ2,1024) bf16

  // fused fp32 -> bf16 conversion
  CvtArgs ca;
  ca.src[0] = x1;  ca.dst[0] = x1b;
  ca.src[1] = x2;  ca.dst[1] = x2b;
  ca.src[2] = Wq1; ca.dst[2] = Wq1b;
  ca.src[3] = Wq2; ca.dst[3] = Wq2b;
  ca.src[4] = Wo1; ca.dst[4] = Wo1b;
  ca.src[5] = Wo2; ca.dst[5] = Wo2b;
  ca.prefix[0] = 0;
  ca.prefix[1] = (int)SX1;
  ca.prefix[2] = (int)(SX1 + SX2);
  ca.prefix[3] = (int)(SX1 + SX2 + SW);
  ca.prefix[4] = (int)(SX1 + SX2 + 2 * SW);
  ca.prefix[5] = (int)(SX1 + SX2 + 2 * SW + SWO);
  ca.prefix[6] = (int)(SX1 + SX2 + 2 * SW + 2 * SWO);
  cvt_all<<<(ca.prefix[6] / 4 + 255) / 256, 256, 0, stream>>>(ca);

  // QKV projections (bf16 out)
  gemm_bf16<1><<<dim3(3 * D_MODEL / 128, BATCH * SEQ1 / 128), 256, 0, stream>>>(
      x1b, Wq1b, bq1, qkv1, BATCH * SEQ1, 3 * D_MODEL, D_MODEL);
  gemm_bf16<1><<<dim3(3 * D_MODEL / 128, BATCH * SEQ2 / 128), 256, 0, stream>>>(
      x2b, Wq2b, bq2, qkv2, BATCH * SEQ2, 3 * D_MODEL, D_MODEL);

  // RMSNorm + RoPE + scatter (bf16; q pre-scaled for exp2 softmax)
  qkv_transform<<<BATCH * (SEQ1 + SEQ2), 256, 0, stream>>>(
      qkv1, qkv2, qs1, ks1, qs2, ks2, qb, kb, vb);

  // V transpose for PV operand
  v_transpose<<<dim3(NTOT / 64, BATCH * N_HEADS), 256, 0, stream>>>(vb, vtb);

  // attention (writes split seq1/seq2 buffers)
  attn_mfma<<<dim3(NTOT / 128, BATCH * N_HEADS), 256, 0, stream>>>(
      qb, kb, vtb, xb1, xb2);

  // output projections: two big GEMMs (f32 out, exact d_out layout)
  gemm_bf16<0><<<dim3(D_MODEL / 128, BATCH * SEQ1 / 128), 256, 0, stream>>>(
      xb1, Wo1b, bo1, out, BATCH * SEQ1, D_MODEL, D_MODEL);
  gemm_bf16<0><<<dim3(D_MODEL / 128, BATCH * SEQ2 / 128), 256, 0, stream>>>(
      xb2, Wo2b, bo2, out + (size_t)BATCH * SEQ1 * D_MODEL,
      BATCH * SEQ2, D_MODEL, D_MODEL);
}

// Round 6
// 312.625 us; speedup vs baseline: 4.8133x; 1.1138x over previous
//
#include <hip/hip_runtime.h>
#include <hip/hip_bf16.h>
#include <math.h>

#define D_MODEL 1024
#define N_HEADS 16
#define HEAD_DIM 64
#define SEQ1 1536
#define SEQ2 512
#define NTOT 2048
#define BATCH 2

typedef __attribute__((ext_vector_type(8))) short bf16x8;   // 8 bf16 = 4 VGPR
typedef __attribute__((ext_vector_type(4))) float f32x4;

__device__ __forceinline__ unsigned short f2bf(float f) {
  unsigned u = __builtin_bit_cast(unsigned, f);
  u += 0x7FFFu + ((u >> 16) & 1u);          // RNE
  return (unsigned short)(u >> 16);
}
__device__ __forceinline__ float bf2f(unsigned short h) {
  unsigned u = ((unsigned)h) << 16;
  return __builtin_bit_cast(float, u);
}

// async global->LDS, 16B per lane. dst wave-uniform; HW writes dst + lane*16.
__device__ __forceinline__ void gload16(const void* g, void* l) {
  __builtin_amdgcn_global_load_lds(
      (const __attribute__((address_space(1))) void*)g,
      (__attribute__((address_space(3))) void*)l, 16, 0, 0);
}

// ---------------------------------------------------------------------------
// Single fused fp32 -> bf16 conversion over 6 segments.
// ---------------------------------------------------------------------------
struct CvtArgs {
  const float* src[6];
  unsigned short* dst[6];
  int prefix[7];
};

__global__ __launch_bounds__(256) void cvt_all(CvtArgs a)
{
  int e = (blockIdx.x * 256 + threadIdx.x) * 4;
  if (e >= a.prefix[6]) return;
  int s = 0;
#pragma unroll
  for (int i = 1; i < 6; ++i) s += (e >= a.prefix[i]) ? 1 : 0;
  int lo = e - a.prefix[s];
  float4 v = *(const float4*)(a.src[s] + lo);
  ushort4 o;
  o.x = f2bf(v.x); o.y = f2bf(v.y); o.z = f2bf(v.z); o.w = f2bf(v.w);
  *(ushort4*)(a.dst[s] + lo) = o;
}

// ---------------------------------------------------------------------------
// Batched bf16 MFMA GEMM over 2 segments: C = A @ W^T + bias.
// 128x128 tile, BK=64, 4 waves; m97 structure (gload_lds w=16, swizzled src).
// ---------------------------------------------------------------------------
struct GemmSeg {
  const unsigned short* A;
  const unsigned short* W;
  const float* bias;
  void* C;
  int N, K, tilesX;
};

template <int WRITE_BF16>
__global__ __launch_bounds__(256) void gemm2(GemmSeg g0, GemmSeg g1, int tiles0)
{
  __shared__ __align__(16) unsigned short Alds[128 * 64];   // 16 KB
  __shared__ __align__(16) unsigned short Blds[128 * 64];
  const int id = blockIdx.x;
  const bool in1 = (id >= tiles0);
  const unsigned short* A = in1 ? g1.A : g0.A;
  const unsigned short* W = in1 ? g1.W : g0.W;
  const float* bias = in1 ? g1.bias : g0.bias;
  void* Cv = in1 ? g1.C : g0.C;
  const int N = in1 ? g1.N : g0.N;
  const int K = in1 ? g1.K : g0.K;
  const int tilesX = in1 ? g1.tilesX : g0.tilesX;
  const int lid = in1 ? id - tiles0 : id;
  const int m0 = (lid / tilesX) * 128, n0 = (lid % tilesX) * 128;

  const int tid = threadIdx.x;
  const int lane = tid & 63, wave = tid >> 6;
  const int wm = wave >> 1, wn = wave & 1;
  const int l15 = lane & 15, l4 = lane >> 4;

  f32x4 acc[4][4];
#pragma unroll
  for (int m = 0; m < 4; ++m)
#pragma unroll
    for (int n = 0; n < 4; ++n)
#pragma unroll
      for (int r = 0; r < 4; ++r) acc[m][n][r] = 0.0f;

  for (int k0 = 0; k0 < K; k0 += 64) {
    __syncthreads();
#pragma unroll
    for (int c = 0; c < 4; ++c) {
      int off = c * 4096 + tid * 16;
      int row = off >> 7;
      int c16g = ((off & 127) >> 4) ^ (row & 7);
      int dstb = c * 4096 + (tid >> 6) * 1024;
      gload16(A + (size_t)(m0 + row) * K + k0 + c16g * 8, (char*)Alds + dstb);
      gload16(W + (size_t)(n0 + row) * K + k0 + c16g * 8, (char*)Blds + dstb);
    }
    __syncthreads();
#pragma unroll
    for (int kk = 0; kk < 2; ++kk) {
      bf16x8 af[4], bfr[4];
#pragma unroll
      for (int m = 0; m < 4; ++m) {
        int r = wm * 64 + m * 16 + l15;
        int colb = (kk * 64 + l4 * 16) ^ ((r & 7) << 4);
        af[m] = *(const bf16x8*)((const char*)Alds + r * 128 + colb);
      }
#pragma unroll
      for (int n = 0; n < 4; ++n) {
        int r = wn * 64 + n * 16 + l15;
        int colb = (kk * 64 + l4 * 16) ^ ((r & 7) << 4);
        bfr[n] = *(const bf16x8*)((const char*)Blds + r * 128 + colb);
      }
#pragma unroll
      for (int m = 0; m < 4; ++m)
#pragma unroll
        for (int n = 0; n < 4; ++n)
          acc[m][n] = __builtin_amdgcn_mfma_f32_16x16x32_bf16(
              af[m], bfr[n], acc[m][n], 0, 0, 0);
    }
  }

#pragma unroll
  for (int m = 0; m < 4; ++m)
#pragma unroll
    for (int n = 0; n < 4; ++n)
#pragma unroll
      for (int r = 0; r < 4; ++r) {
        int row = m0 + wm * 64 + m * 16 + l4 * 4 + r;
        int col = n0 + wn * 64 + n * 16 + l15;
        float v = acc[m][n][r] + bias[col];
        if (WRITE_BF16)
          ((unsigned short*)Cv)[(size_t)row * N + col] = f2bf(v);
        else
          ((float*)Cv)[(size_t)row * N + col] = v;
      }
}

// ---------------------------------------------------------------------------
// RMSNorm + RoPE on bf16 qkv; q pre-scaled by 0.125*log2(e).
// ---------------------------------------------------------------------------
__global__ __launch_bounds__(256) void qkv_transform(
    const unsigned short* __restrict__ qkv1,
    const unsigned short* __restrict__ qkv2,
    const float* __restrict__ qs1, const float* __restrict__ ks1,
    const float* __restrict__ qs2, const float* __restrict__ ks2,
    unsigned short* __restrict__ qO, unsigned short* __restrict__ kO,
    unsigned short* __restrict__ vO)
{
  const int row = blockIdx.x;
  const int lane = threadIdx.x & 63;
  const int wave = threadIdx.x >> 6;
  const float QSCALE = 0.18033688011112042f;  // 0.125 * log2(e)

  const unsigned short* src;
  const float* qs;
  const float* ks;
  int b, pos;
  if (row < BATCH * SEQ1) {
    b = row / SEQ1;
    pos = row % SEQ1;
    src = qkv1 + (size_t)row * (3 * D_MODEL);
    qs = qs1; ks = ks1;
  } else {
    int r2 = row - BATCH * SEQ1;
    b = r2 / SEQ2;
    pos = SEQ1 + (r2 % SEQ2);
    src = qkv2 + (size_t)r2 * (3 * D_MODEL);
    qs = qs2; ks = ks2;
  }

  const int j = lane >> 1;
  const float LOG2_THETA = 13.287712379549449f;
  float inv_freq = exp2f(-((float)(2 * j) / 64.0f) * LOG2_THETA);
  float ang = (float)pos * inv_freq;
  float sn, cs;
  sincosf(ang, &sn, &cs);

  for (int h = wave; h < N_HEADS; h += 4) {
    float xq = bf2f(src[0 * D_MODEL + h * HEAD_DIM + lane]);
    float xk = bf2f(src[1 * D_MODEL + h * HEAD_DIM + lane]);
    float xv = bf2f(src[2 * D_MODEL + h * HEAD_DIM + lane]);

    float sq = xq * xq, sk = xk * xk;
#pragma unroll
    for (int o = 32; o > 0; o >>= 1) {
      sq += __shfl_xor(sq, o);
      sk += __shfl_xor(sk, o);
    }
    float xqn = xq * rsqrtf(sq * (1.0f / 64.0f) + 1e-6f) * qs[lane];
    float xkn = xk * rsqrtf(sk * (1.0f / 64.0f) + 1e-6f) * ks[lane];

    float pq = __shfl_xor(xqn, 1);
    float pk = __shfl_xor(xkn, 1);
    float oq, ok;
    if (lane & 1) { oq = pq * sn + xqn * cs; ok = pk * sn + xkn * cs; }
    else          { oq = xqn * cs - pq * sn; ok = xkn * cs - pk * sn; }

    size_t o = (((size_t)b * N_HEADS + h) * NTOT + pos) * HEAD_DIM + lane;
    qO[o] = f2bf(oq * QSCALE);
    kO[o] = f2bf(ok);
    vO[o] = f2bf(xv);
  }
}

// ---------------------------------------------------------------------------
// V transpose: (BH, NTOT, 64) -> (BH, 64, NTOT), bf16, 64x64 tiles.
// ---------------------------------------------------------------------------
__global__ __launch_bounds__(256) void v_transpose(
    const unsigned short* __restrict__ v, unsigned short* __restrict__ vt)
{
  const int pt = blockIdx.x, bh = blockIdx.y;
  __shared__ unsigned short t[64][72];
  const int tid = threadIdx.x;
  const unsigned short* src = v + ((size_t)bh * NTOT + pt * 64) * 64;
#pragma unroll
  for (int c = 0; c < 2; ++c) {
    int off = c * 4096 + tid * 16;
    int row = off >> 7, c16 = (off & 127) >> 4;
    bf16x8 x = *(const bf16x8*)(src + row * 64 + c16 * 8);
#pragma unroll
    for (int j = 0; j < 8; ++j) t[row][c16 * 8 + j] = (unsigned short)x[j];
  }
  __syncthreads();
  unsigned short* dst = vt + (size_t)bh * 64 * NTOT + pt * 64;
#pragma unroll
  for (int c = 0; c < 2; ++c) {
    int off = c * 4096 + tid * 16;
    int d = off >> 7, p16 = (off & 127) >> 4;
    bf16x8 x;
#pragma unroll
    for (int j = 0; j < 8; ++j) x[j] = (short)t[p16 * 8 + j][d];
    *(bf16x8*)(dst + (size_t)d * NTOT + p16 * 8) = x;
  }
}

// ---------------------------------------------------------------------------
// MFMA flash attention — round-4 VERIFIED core (non-swapped QK^T, exp2-domain
// softmax, per-row defer-max, b16 P scatter, ones-MFMA row-sum) + this round:
// K/V double-buffer (one barrier/iter, stage-after-barrier) and s_setprio
// around the MFMA clusters.
// ---------------------------------------------------------------------------
__global__ __launch_bounds__(256) void attn_mfma(
    const unsigned short* __restrict__ Qg, const unsigned short* __restrict__ Kg,
    const unsigned short* __restrict__ VTg,
    unsigned short* __restrict__ xb1, unsigned short* __restrict__ xb2)
{
  const int qt = blockIdx.x, bh = blockIdx.y;
  const int b = bh >> 4, h = bh & 15;
  const int tid = threadIdx.x, lane = tid & 63, w = tid >> 6;
  const int l15 = lane & 15, l4 = lane >> 4;

  __shared__ __align__(16) unsigned short Klds[2][64 * 64];   // 2 x 8 KB
  __shared__ __align__(16) unsigned short Vlds[2][64 * 64];   // 2 x 8 KB
  __shared__ __align__(16) unsigned short Plds[128 * 64];     // 16 KB

  const size_t base = (size_t)bh * NTOT * HEAD_DIM;
  bf16x8 qf[2][2];
#pragma unroll
  for (int g = 0; g < 2; ++g) {
    const unsigned short* qp =
        Qg + base + (size_t)(qt * 128 + g * 64 + w * 16 + l15) * 64 + l4 * 8;
    qf[g][0] = *(const bf16x8*)qp;
    qf[g][1] = *(const bf16x8*)(qp + 32);
  }

  bf16x8 ones;
#pragma unroll
  for (int i = 0; i < 8; ++i) ones[i] = (short)0x3F80;   // bf16 1.0

  f32x4 acc_o[2][4], acc_l[2];
  float m_run[2][4];
#pragma unroll
  for (int g = 0; g < 2; ++g) {
#pragma unroll
    for (int dt = 0; dt < 4; ++dt)
#pragma unroll
      for (int r = 0; r < 4; ++r) acc_o[g][dt][r] = 0.0f;
#pragma unroll
    for (int r = 0; r < 4; ++r) { acc_l[g][r] = 0.0f; m_run[g][r] = -1e30f; }
  }

  const unsigned short* kp = Kg + base;
  const unsigned short* vtp = VTg + (size_t)bh * HEAD_DIM * NTOT;

#define STAGE(bf, kt)                                                         \
  {                                                                           \
    _Pragma("unroll")                                                         \
    for (int c = 0; c < 2; ++c) {                                             \
      int off = c * 4096 + tid * 16;                                          \
      int row = off >> 7;                                                     \
      int c16g = ((off & 127) >> 4) ^ (row & 7);                              \
      int dstb = c * 4096 + (tid >> 6) * 1024;                                \
      gload16(kp + (size_t)((kt) * 64 + row) * 64 + c16g * 8,                 \
              (char*)Klds[bf] + dstb);                                        \
      gload16(vtp + (size_t)row * NTOT + (kt) * 64 + c16g * 8,                \
              (char*)Vlds[bf] + dstb);                                        \
    }                                                                         \
  }

  STAGE(0, 0);

  for (int kt = 0; kt < NTOT / 64; ++kt) {
    const int cur = kt & 1;
    __syncthreads();   // rendezvous + per-wave vmcnt drain: buf[cur] ready,
                       // all waves past their reads of buf[cur^1]
    if (kt + 1 < NTOT / 64) STAGE(cur ^ 1, kt + 1);

    // S' = (Q*0.125*log2e) K^T  for both row-groups, sharing K reads
    f32x4 sacc[2][4];
#pragma unroll
    for (int g = 0; g < 2; ++g)
#pragma unroll
      for (int ct = 0; ct < 4; ++ct)
#pragma unroll
        for (int r = 0; r < 4; ++r) sacc[g][ct][r] = 0.0f;
    __builtin_amdgcn_s_setprio(1);
#pragma unroll
    for (int kk = 0; kk < 2; ++kk) {
#pragma unroll
      for (int ct = 0; ct < 4; ++ct) {
        int r = ct * 16 + l15;
        int colb = (kk * 64 + l4 * 16) ^ ((r & 7) << 4);
        bf16x8 kf = *(const bf16x8*)((const char*)Klds[cur] + r * 128 + colb);
#pragma unroll
        for (int g = 0; g < 2; ++g)
          sacc[g][ct] = __builtin_amdgcn_mfma_f32_16x16x32_bf16(
              qf[g][kk], kf, sacc[g][ct], 0, 0, 0);
      }
    }
    __builtin_amdgcn_s_setprio(0);

    // online softmax in exp2 domain; P -> swizzled LDS (wave-private rows)
#pragma unroll
    for (int g = 0; g < 2; ++g) {
#pragma unroll
      for (int r = 0; r < 4; ++r) {
        float tm = fmaxf(fmaxf(sacc[g][0][r], sacc[g][1][r]),
                         fmaxf(sacc[g][2][r], sacc[g][3][r]));
#pragma unroll
        for (int o = 1; o < 16; o <<= 1) tm = fmaxf(tm, __shfl_xor(tm, o));
        float mo = m_run[g][r];
        if (tm > mo + 8.0f) {              // rescale path (defer-max)
          float fac = exp2f(mo - tm);
          m_run[g][r] = tm;
#pragma unroll
          for (int dt = 0; dt < 4; ++dt) acc_o[g][dt][r] *= fac;
          acc_l[g][r] *= fac;
        }
        float mc = m_run[g][r];
        int row = g * 64 + w * 16 + l4 * 4 + r;
#pragma unroll
        for (int ct = 0; ct < 4; ++ct) {
          float pv = exp2f(sacc[g][ct][r] - mc);
          int colb = (ct * 32 + l15 * 2) ^ ((row & 7) << 4);
          *(unsigned short*)((char*)Plds + row * 128 + colb) = f2bf(pv);
        }
      }
    }
    // no barrier: each wave reads only its own P rows

    // O += P @ V ; l += P @ 1   (V reads shared across row-groups)
    __builtin_amdgcn_s_setprio(1);
#pragma unroll
    for (int ks = 0; ks < 2; ++ks) {
      bf16x8 pf[2];
#pragma unroll
      for (int g = 0; g < 2; ++g) {
        int pr = g * 64 + w * 16 + l15;
        int pcolb = (ks * 64 + l4 * 16) ^ ((pr & 7) << 4);
        pf[g] = *(const bf16x8*)((const char*)Plds + pr * 128 + pcolb);
      }
#pragma unroll
      for (int dt = 0; dt < 4; ++dt) {
        int vr = dt * 16 + l15;
        int vcolb = (ks * 64 + l4 * 16) ^ ((vr & 7) << 4);
        bf16x8 vf = *(const bf16x8*)((const char*)Vlds[cur] + vr * 128 + vcolb);
#pragma unroll
        for (int g = 0; g < 2; ++g)
          acc_o[g][dt] = __builtin_amdgcn_mfma_f32_16x16x32_bf16(
              pf[g], vf, acc_o[g][dt], 0, 0, 0);
      }
#pragma unroll
      for (int g = 0; g < 2; ++g)
        acc_l[g] = __builtin_amdgcn_mfma_f32_16x16x32_bf16(
            pf[g], ones, acc_l[g], 0, 0, 0);
    }
    __builtin_amdgcn_s_setprio(0);
  }
#undef STAGE

#pragma unroll
  for (int g = 0; g < 2; ++g)
#pragma unroll
    for (int r = 0; r < 4; ++r) {
      int n = qt * 128 + g * 64 + w * 16 + l4 * 4 + r;
      float inv = 1.0f / acc_l[g][r];
      unsigned short* dst;
      if (n < SEQ1) dst = xb1 + ((size_t)b * SEQ1 + n) * D_MODEL;
      else          dst = xb2 + ((size_t)b * SEQ2 + (n - SEQ1)) * D_MODEL;
#pragma unroll
      for (int dt = 0; dt < 4; ++dt)
        dst[h * 64 + dt * 16 + l15] = f2bf(acc_o[g][dt][r] * inv);
    }
}

// ---------------------------------------------------------------------------
extern "C" void kernel_launch(void* const* d_in, const int* in_sizes, int n_in,
                              void* d_out, int out_size, void* d_ws,
                              size_t ws_size, hipStream_t stream)
{
  (void)in_sizes; (void)n_in; (void)out_size; (void)ws_size;

  const float* x1  = (const float*)d_in[0];
  const float* x2  = (const float*)d_in[1];
  const float* Wq1 = (const float*)d_in[2];
  const float* bq1 = (const float*)d_in[3];
  const float* Wq2 = (const float*)d_in[4];
  const float* bq2 = (const float*)d_in[5];
  const float* Wo1 = (const float*)d_in[6];
  const float* bo1 = (const float*)d_in[7];
  const float* Wo2 = (const float*)d_in[8];
  const float* bo2 = (const float*)d_in[9];
  const float* qs1 = (const float*)d_in[10];
  const float* ks1 = (const float*)d_in[11];
  const float* qs2 = (const float*)d_in[12];
  const float* ks2 = (const float*)d_in[13];
  float* out = (float*)d_out;

  unsigned short* ws = (unsigned short*)d_ws;
  const size_t SX1 = (size_t)BATCH * SEQ1 * D_MODEL;
  const size_t SX2 = (size_t)BATCH * SEQ2 * D_MODEL;
  const size_t SW  = (size_t)3 * D_MODEL * D_MODEL;
  const size_t SWO = (size_t)D_MODEL * D_MODEL;
  const size_t SQ1 = (size_t)BATCH * SEQ1 * 3 * D_MODEL;
  const size_t SQ2 = (size_t)BATCH * SEQ2 * 3 * D_MODEL;
  const size_t SH  = (size_t)BATCH * N_HEADS * NTOT * HEAD_DIM;

  unsigned short* x1b  = ws;
  unsigned short* x2b  = x1b + SX1;
  unsigned short* Wq1b = x2b + SX2;
  unsigned short* Wq2b = Wq1b + SW;
  unsigned short* Wo1b = Wq2b + SW;
  unsigned short* Wo2b = Wo1b + SWO;
  unsigned short* qkv1 = Wo2b + SWO;
  unsigned short* qkv2 = qkv1 + SQ1;
  unsigned short* qb   = qkv2 + SQ2;
  unsigned short* kb   = qb + SH;
  unsigned short* vb   = kb + SH;
  unsigned short* vtb  = vb + SH;
  unsigned short* xb1  = vtb + SH;          // (B,SEQ1,1024) bf16
  unsigned short* xb2  = xb1 + SX1;         // (B,SEQ2,1024) bf16

  // fused fp32 -> bf16 conversion
  CvtArgs ca;
  ca.src[0] = x1;  ca.dst[0] = x1b;
  ca.src[1] = x2;  ca.dst[1] = x2b;
  ca.src[2] = Wq1; ca.dst[2] = Wq1b;
  ca.src[3] = Wq2; ca.dst[3] = Wq2b;
  ca.src[4] = Wo1; ca.dst[4] = Wo1b;
  ca.src[5] = Wo2; ca.dst[5] = Wo2b;
  ca.prefix[0] = 0;
  ca.prefix[1] = (int)SX1;
  ca.prefix[2] = (int)(SX1 + SX2);
  ca.prefix[3] = (int)(SX1 + SX2 + SW);
  ca.prefix[4] = (int)(SX1 + SX2 + 2 * SW);
  ca.prefix[5] = (int)(SX1 + SX2 + 2 * SW + SWO);
  ca.prefix[6] = (int)(SX1 + SX2 + 2 * SW + 2 * SWO);
  cvt_all<<<(ca.prefix[6] / 4 + 255) / 256, 256, 0, stream>>>(ca);

  // QKV projections: one batched dispatch (bf16 out)
  {
    GemmSeg s0{x1b, Wq1b, bq1, qkv1, 3 * D_MODEL, D_MODEL, 3 * D_MODEL / 128};
    GemmSeg s1{x2b, Wq2b, bq2, qkv2, 3 * D_MODEL, D_MODEL, 3 * D_MODEL / 128};
    int t0 = (BATCH * SEQ1 / 128) * (3 * D_MODEL / 128);   // 576
    int t1 = (BATCH * SEQ2 / 128) * (3 * D_MODEL / 128);   // 192
    gemm2<1><<<t0 + t1, 256, 0, stream>>>(s0, s1, t0);
  }

  // RMSNorm + RoPE + scatter
  qkv_transform<<<BATCH * (SEQ1 + SEQ2), 256, 0, stream>>>(
      qkv1, qkv2, qs1, ks1, qs2, ks2, qb, kb, vb);

  // V transpose for PV operand
  v_transpose<<<dim3(NTOT / 64, BATCH * N_HEADS), 256, 0, stream>>>(vb, vtb);

  // attention
  attn_mfma<<<dim3(NTOT / 128, BATCH * N_HEADS), 256, 0, stream>>>(
      qb, kb, vtb, xb1, xb2);

  // output projections: one batched dispatch (f32 out)
  {
    GemmSeg s0{xb1, Wo1b, bo1, out, D_MODEL, D_MODEL, D_MODEL / 128};
    GemmSeg s1{xb2, Wo2b, bo2, out + (size_t)BATCH * SEQ1 * D_MODEL,
               D_MODEL, D_MODEL, D_MODEL / 128};
    int t0 = (BATCH * SEQ1 / 128) * (D_MODEL / 128);   // 192
    int t1 = (BATCH * SEQ2 / 128) * (D_MODEL / 128);   // 64
    gemm2<0><<<t0 + t1, 256, 0, stream>>>(s0, s1, t0);
  }
}

// Round 7
// 291.268 us; speedup vs baseline: 5.1662x; 1.0733x over previous
//
#include <hip/hip_runtime.h>
#include <hip/hip_bf16.h>
#include <math.h>

#define D_MODEL 1024
#define N_HEADS 16
#define HEAD_DIM 64
#define SEQ1 1536
#define SEQ2 512
#define NTOT 2048
#define BATCH 2

typedef __attribute__((ext_vector_type(8))) short bf16x8;   // 8 bf16 = 4 VGPR
typedef __attribute__((ext_vector_type(4))) float f32x4;

__device__ __forceinline__ unsigned short f2bf(float f) {
  unsigned u = __builtin_bit_cast(unsigned, f);
  u += 0x7FFFu + ((u >> 16) & 1u);          // RNE
  return (unsigned short)(u >> 16);
}
__device__ __forceinline__ float bf2f(unsigned short h) {
  unsigned u = ((unsigned)h) << 16;
  return __builtin_bit_cast(float, u);
}

// async global->LDS, 16B per lane. dst wave-uniform; HW writes dst + lane*16.
__device__ __forceinline__ void gload16(const void* g, void* l) {
  __builtin_amdgcn_global_load_lds(
      (const __attribute__((address_space(1))) void*)g,
      (__attribute__((address_space(3))) void*)l, 16, 0, 0);
}

// ---------------------------------------------------------------------------
// Single fused fp32 -> bf16 conversion over 6 segments.
// ---------------------------------------------------------------------------
struct CvtArgs {
  const float* src[6];
  unsigned short* dst[6];
  int prefix[7];
};

__global__ __launch_bounds__(256) void cvt_all(CvtArgs a)
{
  int e = (blockIdx.x * 256 + threadIdx.x) * 4;
  if (e >= a.prefix[6]) return;
  int s = 0;
#pragma unroll
  for (int i = 1; i < 6; ++i) s += (e >= a.prefix[i]) ? 1 : 0;
  int lo = e - a.prefix[s];
  float4 v = *(const float4*)(a.src[s] + lo);
  ushort4 o;
  o.x = f2bf(v.x); o.y = f2bf(v.y); o.z = f2bf(v.z); o.w = f2bf(v.w);
  *(ushort4*)(a.dst[s] + lo) = o;
}

// ---------------------------------------------------------------------------
// Batched bf16 MFMA GEMM over 2 segments: C = A @ W^T + bias.
// 128x128 tile, BK=64, 4 waves; m97 structure (gload_lds w=16, swizzled src).
// ---------------------------------------------------------------------------
struct GemmSeg {
  const unsigned short* A;
  const unsigned short* W;
  const float* bias;
  void* C;
  int N, K, tilesX;
};

template <int WRITE_BF16>
__global__ __launch_bounds__(256) void gemm2(GemmSeg g0, GemmSeg g1, int tiles0)
{
  __shared__ __align__(16) unsigned short Alds[128 * 64];   // 16 KB
  __shared__ __align__(16) unsigned short Blds[128 * 64];
  const int id = blockIdx.x;
  const bool in1 = (id >= tiles0);
  const unsigned short* A = in1 ? g1.A : g0.A;
  const unsigned short* W = in1 ? g1.W : g0.W;
  const float* bias = in1 ? g1.bias : g0.bias;
  void* Cv = in1 ? g1.C : g0.C;
  const int N = in1 ? g1.N : g0.N;
  const int K = in1 ? g1.K : g0.K;
  const int tilesX = in1 ? g1.tilesX : g0.tilesX;
  const int lid = in1 ? id - tiles0 : id;
  const int m0 = (lid / tilesX) * 128, n0 = (lid % tilesX) * 128;

  const int tid = threadIdx.x;
  const int lane = tid & 63, wave = tid >> 6;
  const int wm = wave >> 1, wn = wave & 1;
  const int l15 = lane & 15, l4 = lane >> 4;

  f32x4 acc[4][4];
#pragma unroll
  for (int m = 0; m < 4; ++m)
#pragma unroll
    for (int n = 0; n < 4; ++n)
#pragma unroll
      for (int r = 0; r < 4; ++r) acc[m][n][r] = 0.0f;

  for (int k0 = 0; k0 < K; k0 += 64) {
    __syncthreads();
#pragma unroll
    for (int c = 0; c < 4; ++c) {
      int off = c * 4096 + tid * 16;
      int row = off >> 7;
      int c16g = ((off & 127) >> 4) ^ (row & 7);
      int dstb = c * 4096 + (tid >> 6) * 1024;
      gload16(A + (size_t)(m0 + row) * K + k0 + c16g * 8, (char*)Alds + dstb);
      gload16(W + (size_t)(n0 + row) * K + k0 + c16g * 8, (char*)Blds + dstb);
    }
    __syncthreads();
#pragma unroll
    for (int kk = 0; kk < 2; ++kk) {
      bf16x8 af[4], bfr[4];
#pragma unroll
      for (int m = 0; m < 4; ++m) {
        int r = wm * 64 + m * 16 + l15;
        int colb = (kk * 64 + l4 * 16) ^ ((r & 7) << 4);
        af[m] = *(const bf16x8*)((const char*)Alds + r * 128 + colb);
      }
#pragma unroll
      for (int n = 0; n < 4; ++n) {
        int r = wn * 64 + n * 16 + l15;
        int colb = (kk * 64 + l4 * 16) ^ ((r & 7) << 4);
        bfr[n] = *(const bf16x8*)((const char*)Blds + r * 128 + colb);
      }
#pragma unroll
      for (int m = 0; m < 4; ++m)
#pragma unroll
        for (int n = 0; n < 4; ++n)
          acc[m][n] = __builtin_amdgcn_mfma_f32_16x16x32_bf16(
              af[m], bfr[n], acc[m][n], 0, 0, 0);
    }
  }

#pragma unroll
  for (int m = 0; m < 4; ++m)
#pragma unroll
    for (int n = 0; n < 4; ++n)
#pragma unroll
      for (int r = 0; r < 4; ++r) {
        int row = m0 + wm * 64 + m * 16 + l4 * 4 + r;
        int col = n0 + wn * 64 + n * 16 + l15;
        float v = acc[m][n][r] + bias[col];
        if (WRITE_BF16)
          ((unsigned short*)Cv)[(size_t)row * N + col] = f2bf(v);
        else
          ((float*)Cv)[(size_t)row * N + col] = v;
      }
}

// ---------------------------------------------------------------------------
// RMSNorm + RoPE on bf16 qkv; q pre-scaled by 0.125*log2(e).
// ---------------------------------------------------------------------------
__global__ __launch_bounds__(256) void qkv_transform(
    const unsigned short* __restrict__ qkv1,
    const unsigned short* __restrict__ qkv2,
    const float* __restrict__ qs1, const float* __restrict__ ks1,
    const float* __restrict__ qs2, const float* __restrict__ ks2,
    unsigned short* __restrict__ qO, unsigned short* __restrict__ kO,
    unsigned short* __restrict__ vO)
{
  const int row = blockIdx.x;
  const int lane = threadIdx.x & 63;
  const int wave = threadIdx.x >> 6;
  const float QSCALE = 0.18033688011112042f;  // 0.125 * log2(e)

  const unsigned short* src;
  const float* qs;
  const float* ks;
  int b, pos;
  if (row < BATCH * SEQ1) {
    b = row / SEQ1;
    pos = row % SEQ1;
    src = qkv1 + (size_t)row * (3 * D_MODEL);
    qs = qs1; ks = ks1;
  } else {
    int r2 = row - BATCH * SEQ1;
    b = r2 / SEQ2;
    pos = SEQ1 + (r2 % SEQ2);
    src = qkv2 + (size_t)r2 * (3 * D_MODEL);
    qs = qs2; ks = ks2;
  }

  const int j = lane >> 1;
  const float LOG2_THETA = 13.287712379549449f;
  float inv_freq = exp2f(-((float)(2 * j) / 64.0f) * LOG2_THETA);
  float ang = (float)pos * inv_freq;
  float sn, cs;
  sincosf(ang, &sn, &cs);

  for (int h = wave; h < N_HEADS; h += 4) {
    float xq = bf2f(src[0 * D_MODEL + h * HEAD_DIM + lane]);
    float xk = bf2f(src[1 * D_MODEL + h * HEAD_DIM + lane]);
    float xv = bf2f(src[2 * D_MODEL + h * HEAD_DIM + lane]);

    float sq = xq * xq, sk = xk * xk;
#pragma unroll
    for (int o = 32; o > 0; o >>= 1) {
      sq += __shfl_xor(sq, o);
      sk += __shfl_xor(sk, o);
    }
    float xqn = xq * rsqrtf(sq * (1.0f / 64.0f) + 1e-6f) * qs[lane];
    float xkn = xk * rsqrtf(sk * (1.0f / 64.0f) + 1e-6f) * ks[lane];

    float pq = __shfl_xor(xqn, 1);
    float pk = __shfl_xor(xkn, 1);
    float oq, ok;
    if (lane & 1) { oq = pq * sn + xqn * cs; ok = pk * sn + xkn * cs; }
    else          { oq = xqn * cs - pq * sn; ok = xkn * cs - pk * sn; }

    size_t o = (((size_t)b * N_HEADS + h) * NTOT + pos) * HEAD_DIM + lane;
    qO[o] = f2bf(oq * QSCALE);
    kO[o] = f2bf(ok);
    vO[o] = f2bf(xv);
  }
}

// ---------------------------------------------------------------------------
// V transpose: (BH, NTOT, 64) -> (BH, 64, NTOT), bf16, 64x64 tiles.
// ---------------------------------------------------------------------------
__global__ __launch_bounds__(256) void v_transpose(
    const unsigned short* __restrict__ v, unsigned short* __restrict__ vt)
{
  const int pt = blockIdx.x, bh = blockIdx.y;
  __shared__ unsigned short t[64][72];
  const int tid = threadIdx.x;
  const unsigned short* src = v + ((size_t)bh * NTOT + pt * 64) * 64;
#pragma unroll
  for (int c = 0; c < 2; ++c) {
    int off = c * 4096 + tid * 16;
    int row = off >> 7, c16 = (off & 127) >> 4;
    bf16x8 x = *(const bf16x8*)(src + row * 64 + c16 * 8);
#pragma unroll
    for (int j = 0; j < 8; ++j) t[row][c16 * 8 + j] = (unsigned short)x[j];
  }
  __syncthreads();
  unsigned short* dst = vt + (size_t)bh * 64 * NTOT + pt * 64;
#pragma unroll
  for (int c = 0; c < 2; ++c) {
    int off = c * 4096 + tid * 16;
    int d = off >> 7, p16 = (off & 127) >> 4;
    bf16x8 x;
#pragma unroll
    for (int j = 0; j < 8; ++j) x[j] = (short)t[p16 * 8 + j][d];
    *(bf16x8*)(dst + (size_t)d * NTOT + p16 * 8) = x;
  }
}

// ---------------------------------------------------------------------------
// MFMA flash attention, swapped-QK^T (retry of round 5 with verified f2bf
// bit-pack replacing the cvt_pk asm — the single isolated change).
// S^T = mfma(K,Q): lane holds S[k = ct*16 + l4*4 + r][q = l15] -> scalar m/l
// per lane, 15-op local max + 2 shuffles, P packed to b64 LDS writes,
// row-sum from f32 p's (no ones-MFMA). K/V dbuf + setprio kept from round 6.
// ---------------------------------------------------------------------------
__global__ __launch_bounds__(256) void attn_mfma(
    const unsigned short* __restrict__ Qg, const unsigned short* __restrict__ Kg,
    const unsigned short* __restrict__ VTg,
    unsigned short* __restrict__ xb1, unsigned short* __restrict__ xb2)
{
  const int qt = blockIdx.x, bh = blockIdx.y;
  const int b = bh >> 4, h = bh & 15;
  const int tid = threadIdx.x, lane = tid & 63, w = tid >> 6;
  const int l15 = lane & 15, l4 = lane >> 4;

  __shared__ __align__(16) unsigned short Klds[2][64 * 64];   // 2 x 8 KB
  __shared__ __align__(16) unsigned short Vlds[2][64 * 64];   // 2 x 8 KB
  __shared__ __align__(16) unsigned short Plds[128 * 64];     // 16 KB

  const size_t base = (size_t)bh * NTOT * HEAD_DIM;
  bf16x8 qf[2][2];
#pragma unroll
  for (int g = 0; g < 2; ++g) {
    const unsigned short* qp =
        Qg + base + (size_t)(qt * 128 + g * 64 + w * 16 + l15) * 64 + l4 * 8;
    qf[g][0] = *(const bf16x8*)qp;
    qf[g][1] = *(const bf16x8*)(qp + 32);
  }

  f32x4 acc_o[2][4];
  float m_run[2], l_run[2];
#pragma unroll
  for (int g = 0; g < 2; ++g) {
#pragma unroll
    for (int dt = 0; dt < 4; ++dt)
#pragma unroll
      for (int r = 0; r < 4; ++r) acc_o[g][dt][r] = 0.0f;
    m_run[g] = -1e30f;
    l_run[g] = 0.0f;
  }

  const unsigned short* kp = Kg + base;
  const unsigned short* vtp = VTg + (size_t)bh * HEAD_DIM * NTOT;

#define STAGE(bf, kt)                                                         \
  {                                                                           \
    _Pragma("unroll")                                                         \
    for (int c = 0; c < 2; ++c) {                                             \
      int off = c * 4096 + tid * 16;                                          \
      int row = off >> 7;                                                     \
      int c16g = ((off & 127) >> 4) ^ (row & 7);                              \
      int dstb = c * 4096 + (tid >> 6) * 1024;                                \
      gload16(kp + (size_t)((kt) * 64 + row) * 64 + c16g * 8,                 \
              (char*)Klds[bf] + dstb);                                        \
      gload16(vtp + (size_t)row * NTOT + (kt) * 64 + c16g * 8,                \
              (char*)Vlds[bf] + dstb);                                        \
    }                                                                         \
  }

  STAGE(0, 0);

  for (int kt = 0; kt < NTOT / 64; ++kt) {
    const int cur = kt & 1;
    __syncthreads();   // rendezvous + per-wave vmcnt drain: buf[cur] ready,
                       // all waves past their reads of buf[cur^1]
    if (kt + 1 < NTOT / 64) STAGE(cur ^ 1, kt + 1);

    // S^T = mfma(K, Q): sacc[g][ct][r] = S[k = ct*16 + l4*4 + r][q = l15]
    f32x4 sacc[2][4];
#pragma unroll
    for (int g = 0; g < 2; ++g)
#pragma unroll
      for (int ct = 0; ct < 4; ++ct)
#pragma unroll
        for (int r = 0; r < 4; ++r) sacc[g][ct][r] = 0.0f;
    __builtin_amdgcn_s_setprio(1);
#pragma unroll
    for (int kk = 0; kk < 2; ++kk) {
#pragma unroll
      for (int ct = 0; ct < 4; ++ct) {
        int r = ct * 16 + l15;
        int colb = (kk * 64 + l4 * 16) ^ ((r & 7) << 4);
        bf16x8 kf = *(const bf16x8*)((const char*)Klds[cur] + r * 128 + colb);
#pragma unroll
        for (int g = 0; g < 2; ++g)
          sacc[g][ct] = __builtin_amdgcn_mfma_f32_16x16x32_bf16(
              kf, qf[g][kk], sacc[g][ct], 0, 0, 0);
      }
    }
    __builtin_amdgcn_s_setprio(0);

    // softmax: each lane owns one q-column (q = l15) per row-group
#pragma unroll
    for (int g = 0; g < 2; ++g) {
      float tm = fmaxf(fmaxf(sacc[g][0][0], sacc[g][0][1]),
                       fmaxf(sacc[g][0][2], sacc[g][0][3]));
#pragma unroll
      for (int ct = 1; ct < 4; ++ct)
        tm = fmaxf(tm, fmaxf(fmaxf(sacc[g][ct][0], sacc[g][ct][1]),
                             fmaxf(sacc[g][ct][2], sacc[g][ct][3])));
      tm = fmaxf(tm, __shfl_xor(tm, 16));
      tm = fmaxf(tm, __shfl_xor(tm, 32));
      float mo = m_run[g];
      if (!__all(tm <= mo + 8.0f)) {       // defer-max (THR=8, exp2 domain)
        float mn = fmaxf(mo, tm);
        float fac = exp2f(mo - mn);
        m_run[g] = mn;
        l_run[g] *= fac;
#pragma unroll
        for (int r = 0; r < 4; ++r) {
          float fr = __shfl(fac, l4 * 4 + r);
#pragma unroll
          for (int dt = 0; dt < 4; ++dt) acc_o[g][dt][r] *= fr;
        }
      }
      float mc = m_run[g];
      float rs = 0.0f;
      int qrow = g * 64 + w * 16 + l15;
#pragma unroll
      for (int ct = 0; ct < 4; ++ct) {
        float p0 = exp2f(sacc[g][ct][0] - mc);
        float p1 = exp2f(sacc[g][ct][1] - mc);
        float p2 = exp2f(sacc[g][ct][2] - mc);
        float p3 = exp2f(sacc[g][ct][3] - mc);
        rs += (p0 + p1) + (p2 + p3);
        uint2 pw;
        pw.x = (unsigned)f2bf(p0) | ((unsigned)f2bf(p1) << 16);
        pw.y = (unsigned)f2bf(p2) | ((unsigned)f2bf(p3) << 16);
        *(uint2*)((char*)Plds + qrow * 128 +
                  ((ct * 32 + l4 * 8) ^ ((qrow & 7) << 4))) = pw;
      }
      rs += __shfl_xor(rs, 16);
      rs += __shfl_xor(rs, 32);
      l_run[g] += rs;
    }
    // no barrier: P rows are wave-private (same-wave DS ordering)

    // O += P @ V
    __builtin_amdgcn_s_setprio(1);
#pragma unroll
    for (int ks = 0; ks < 2; ++ks) {
      bf16x8 pf[2];
#pragma unroll
      for (int g = 0; g < 2; ++g) {
        int pr = g * 64 + w * 16 + l15;
        int pcolb = (ks * 64 + l4 * 16) ^ ((pr & 7) << 4);
        pf[g] = *(const bf16x8*)((const char*)Plds + pr * 128 + pcolb);
      }
#pragma unroll
      for (int dt = 0; dt < 4; ++dt) {
        int vr = dt * 16 + l15;
        int vcolb = (ks * 64 + l4 * 16) ^ ((vr & 7) << 4);
        bf16x8 vf = *(const bf16x8*)((const char*)Vlds[cur] + vr * 128 + vcolb);
#pragma unroll
        for (int g = 0; g < 2; ++g)
          acc_o[g][dt] = __builtin_amdgcn_mfma_f32_16x16x32_bf16(
              pf[g], vf, acc_o[g][dt], 0, 0, 0);
      }
    }
    __builtin_amdgcn_s_setprio(0);
  }
#undef STAGE

#pragma unroll
  for (int g = 0; g < 2; ++g) {
    float inv = 1.0f / l_run[g];           // per q = l15
#pragma unroll
    for (int r = 0; r < 4; ++r) {
      float ir = __shfl(inv, l4 * 4 + r);
      int n = qt * 128 + g * 64 + w * 16 + l4 * 4 + r;
      unsigned short* dst;
      if (n < SEQ1) dst = xb1 + ((size_t)b * SEQ1 + n) * D_MODEL;
      else          dst = xb2 + ((size_t)b * SEQ2 + (n - SEQ1)) * D_MODEL;
#pragma unroll
      for (int dt = 0; dt < 4; ++dt)
        dst[h * 64 + dt * 16 + l15] = f2bf(acc_o[g][dt][r] * ir);
    }
  }
}

// ---------------------------------------------------------------------------
extern "C" void kernel_launch(void* const* d_in, const int* in_sizes, int n_in,
                              void* d_out, int out_size, void* d_ws,
                              size_t ws_size, hipStream_t stream)
{
  (void)in_sizes; (void)n_in; (void)out_size; (void)ws_size;

  const float* x1  = (const float*)d_in[0];
  const float* x2  = (const float*)d_in[1];
  const float* Wq1 = (const float*)d_in[2];
  const float* bq1 = (const float*)d_in[3];
  const float* Wq2 = (const float*)d_in[4];
  const float* bq2 = (const float*)d_in[5];
  const float* Wo1 = (const float*)d_in[6];
  const float* bo1 = (const float*)d_in[7];
  const float* Wo2 = (const float*)d_in[8];
  const float* bo2 = (const float*)d_in[9];
  const float* qs1 = (const float*)d_in[10];
  const float* ks1 = (const float*)d_in[11];
  const float* qs2 = (const float*)d_in[12];
  const float* ks2 = (const float*)d_in[13];
  float* out = (float*)d_out;

  unsigned short* ws = (unsigned short*)d_ws;
  const size_t SX1 = (size_t)BATCH * SEQ1 * D_MODEL;
  const size_t SX2 = (size_t)BATCH * SEQ2 * D_MODEL;
  const size_t SW  = (size_t)3 * D_MODEL * D_MODEL;
  const size_t SWO = (size_t)D_MODEL * D_MODEL;
  const size_t SQ1 = (size_t)BATCH * SEQ1 * 3 * D_MODEL;
  const size_t SQ2 = (size_t)BATCH * SEQ2 * 3 * D_MODEL;
  const size_t SH  = (size_t)BATCH * N_HEADS * NTOT * HEAD_DIM;

  unsigned short* x1b  = ws;
  unsigned short* x2b  = x1b + SX1;
  unsigned short* Wq1b = x2b + SX2;
  unsigned short* Wq2b = Wq1b + SW;
  unsigned short* Wo1b = Wq2b + SW;
  unsigned short* Wo2b = Wo1b + SWO;
  unsigned short* qkv1 = Wo2b + SWO;
  unsigned short* qkv2 = qkv1 + SQ1;
  unsigned short* qb   = qkv2 + SQ2;
  unsigned short* kb   = qb + SH;
  unsigned short* vb   = kb + SH;
  unsigned short* vtb  = vb + SH;
  unsigned short* xb1  = vtb + SH;          // (B,SEQ1,1024) bf16
  unsigned short* xb2  = xb1 + SX1;         // (B,SEQ2,1024) bf16

  // fused fp32 -> bf16 conversion
  CvtArgs ca;
  ca.src[0] = x1;  ca.dst[0] = x1b;
  ca.src[1] = x2;  ca.dst[1] = x2b;
  ca.src[2] = Wq1; ca.dst[2] = Wq1b;
  ca.src[3] = Wq2; ca.dst[3] = Wq2b;
  ca.src[4] = Wo1; ca.dst[4] = Wo1b;
  ca.src[5] = Wo2; ca.dst[5] = Wo2b;
  ca.prefix[0] = 0;
  ca.prefix[1] = (int)SX1;
  ca.prefix[2] = (int)(SX1 + SX2);
  ca.prefix[3] = (int)(SX1 + SX2 + SW);
  ca.prefix[4] = (int)(SX1 + SX2 + 2 * SW);
  ca.prefix[5] = (int)(SX1 + SX2 + 2 * SW + SWO);
  ca.prefix[6] = (int)(SX1 + SX2 + 2 * SW + 2 * SWO);
  cvt_all<<<(ca.prefix[6] / 4 + 255) / 256, 256, 0, stream>>>(ca);

  // QKV projections: one batched dispatch (bf16 out)
  {
    GemmSeg s0{x1b, Wq1b, bq1, qkv1, 3 * D_MODEL, D_MODEL, 3 * D_MODEL / 128};
    GemmSeg s1{x2b, Wq2b, bq2, qkv2, 3 * D_MODEL, D_MODEL, 3 * D_MODEL / 128};
    int t0 = (BATCH * SEQ1 / 128) * (3 * D_MODEL / 128);   // 576
    int t1 = (BATCH * SEQ2 / 128) * (3 * D_MODEL / 128);   // 192
    gemm2<1><<<t0 + t1, 256, 0, stream>>>(s0, s1, t0);
  }

  // RMSNorm + RoPE + scatter
  qkv_transform<<<BATCH * (SEQ1 + SEQ2), 256, 0, stream>>>(
      qkv1, qkv2, qs1, ks1, qs2, ks2, qb, kb, vb);

  // V transpose for PV operand
  v_transpose<<<dim3(NTOT / 64, BATCH * N_HEADS), 256, 0, stream>>>(vb, vtb);

  // attention
  attn_mfma<<<dim3(NTOT / 128, BATCH * N_HEADS), 256, 0, stream>>>(
      qb, kb, vtb, xb1, xb2);

  // output projections: one batched dispatch (f32 out)
  {
    GemmSeg s0{xb1, Wo1b, bo1, out, D_MODEL, D_MODEL, D_MODEL / 128};
    GemmSeg s1{xb2, Wo2b, bo2, out + (size_t)BATCH * SEQ1 * D_MODEL,
               D_MODEL, D_MODEL, D_MODEL / 128};
    int t0 = (BATCH * SEQ1 / 128) * (D_MODEL / 128);   // 192
    int t1 = (BATCH * SEQ2 / 128) * (D_MODEL / 128);   // 64
    gemm2<0><<<t0 + t1, 256, 0, stream>>>(s0, s1, t0);
  }
}

// Round 8
// 287.517 us; speedup vs baseline: 5.2336x; 1.0130x over previous
//
#include <hip/hip_runtime.h>
#include <hip/hip_bf16.h>
#include <math.h>

#define D_MODEL 1024
#define N_HEADS 16
#define HEAD_DIM 64
#define SEQ1 1536
#define SEQ2 512
#define NTOT 2048
#define BATCH 2

typedef __attribute__((ext_vector_type(8))) short bf16x8;   // 8 bf16 = 4 VGPR
typedef __attribute__((ext_vector_type(4))) float f32x4;

__device__ __forceinline__ unsigned short f2bf(float f) {
  unsigned u = __builtin_bit_cast(unsigned, f);
  u += 0x7FFFu + ((u >> 16) & 1u);          // RNE
  return (unsigned short)(u >> 16);
}
__device__ __forceinline__ float bf2f(unsigned short h) {
  unsigned u = ((unsigned)h) << 16;
  return __builtin_bit_cast(float, u);
}

// async global->LDS, 16B per lane. dst wave-uniform; HW writes dst + lane*16.
__device__ __forceinline__ void gload16(const void* g, void* l) {
  __builtin_amdgcn_global_load_lds(
      (const __attribute__((address_space(1))) void*)g,
      (__attribute__((address_space(3))) void*)l, 16, 0, 0);
}

// ---------------------------------------------------------------------------
// Single fused fp32 -> bf16 conversion over 6 segments.
// ---------------------------------------------------------------------------
struct CvtArgs {
  const float* src[6];
  unsigned short* dst[6];
  int prefix[7];
};

__global__ __launch_bounds__(256) void cvt_all(CvtArgs a)
{
  int e = (blockIdx.x * 256 + threadIdx.x) * 4;
  if (e >= a.prefix[6]) return;
  int s = 0;
#pragma unroll
  for (int i = 1; i < 6; ++i) s += (e >= a.prefix[i]) ? 1 : 0;
  int lo = e - a.prefix[s];
  float4 v = *(const float4*)(a.src[s] + lo);
  ushort4 o;
  o.x = f2bf(v.x); o.y = f2bf(v.y); o.z = f2bf(v.z); o.w = f2bf(v.w);
  *(ushort4*)(a.dst[s] + lo) = o;
}

// ---------------------------------------------------------------------------
// Batched bf16 MFMA GEMM over 2 segments: C = A @ W^T + bias.
// 128x128 tile, BK=64, 4 waves; m97 structure (gload_lds w=16, swizzled src).
// ---------------------------------------------------------------------------
struct GemmSeg {
  const unsigned short* A;
  const unsigned short* W;
  const float* bias;
  void* C;
  int N, K, tilesX;
};

template <int WRITE_BF16>
__global__ __launch_bounds__(256) void gemm2(GemmSeg g0, GemmSeg g1, int tiles0)
{
  __shared__ __align__(16) unsigned short Alds[128 * 64];   // 16 KB
  __shared__ __align__(16) unsigned short Blds[128 * 64];
  const int id = blockIdx.x;
  const bool in1 = (id >= tiles0);
  const unsigned short* A = in1 ? g1.A : g0.A;
  const unsigned short* W = in1 ? g1.W : g0.W;
  const float* bias = in1 ? g1.bias : g0.bias;
  void* Cv = in1 ? g1.C : g0.C;
  const int N = in1 ? g1.N : g0.N;
  const int K = in1 ? g1.K : g0.K;
  const int tilesX = in1 ? g1.tilesX : g0.tilesX;
  const int lid = in1 ? id - tiles0 : id;
  const int m0 = (lid / tilesX) * 128, n0 = (lid % tilesX) * 128;

  const int tid = threadIdx.x;
  const int lane = tid & 63, wave = tid >> 6;
  const int wm = wave >> 1, wn = wave & 1;
  const int l15 = lane & 15, l4 = lane >> 4;

  f32x4 acc[4][4];
#pragma unroll
  for (int m = 0; m < 4; ++m)
#pragma unroll
    for (int n = 0; n < 4; ++n)
#pragma unroll
      for (int r = 0; r < 4; ++r) acc[m][n][r] = 0.0f;

  for (int k0 = 0; k0 < K; k0 += 64) {
    __syncthreads();
#pragma unroll
    for (int c = 0; c < 4; ++c) {
      int off = c * 4096 + tid * 16;
      int row = off >> 7;
      int c16g = ((off & 127) >> 4) ^ (row & 7);
      int dstb = c * 4096 + (tid >> 6) * 1024;
      gload16(A + (size_t)(m0 + row) * K + k0 + c16g * 8, (char*)Alds + dstb);
      gload16(W + (size_t)(n0 + row) * K + k0 + c16g * 8, (char*)Blds + dstb);
    }
    __syncthreads();
#pragma unroll
    for (int kk = 0; kk < 2; ++kk) {
      bf16x8 af[4], bfr[4];
#pragma unroll
      for (int m = 0; m < 4; ++m) {
        int r = wm * 64 + m * 16 + l15;
        int colb = (kk * 64 + l4 * 16) ^ ((r & 7) << 4);
        af[m] = *(const bf16x8*)((const char*)Alds + r * 128 + colb);
      }
#pragma unroll
      for (int n = 0; n < 4; ++n) {
        int r = wn * 64 + n * 16 + l15;
        int colb = (kk * 64 + l4 * 16) ^ ((r & 7) << 4);
        bfr[n] = *(const bf16x8*)((const char*)Blds + r * 128 + colb);
      }
#pragma unroll
      for (int m = 0; m < 4; ++m)
#pragma unroll
        for (int n = 0; n < 4; ++n)
          acc[m][n] = __builtin_amdgcn_mfma_f32_16x16x32_bf16(
              af[m], bfr[n], acc[m][n], 0, 0, 0);
    }
  }

#pragma unroll
  for (int m = 0; m < 4; ++m)
#pragma unroll
    for (int n = 0; n < 4; ++n)
#pragma unroll
      for (int r = 0; r < 4; ++r) {
        int row = m0 + wm * 64 + m * 16 + l4 * 4 + r;
        int col = n0 + wn * 64 + n * 16 + l15;
        float v = acc[m][n][r] + bias[col];
        if (WRITE_BF16)
          ((unsigned short*)Cv)[(size_t)row * N + col] = f2bf(v);
        else
          ((float*)Cv)[(size_t)row * N + col] = v;
      }
}

// ---------------------------------------------------------------------------
// RMSNorm + RoPE on bf16 qkv; q pre-scaled by 0.125*log2(e).
// ---------------------------------------------------------------------------
__global__ __launch_bounds__(256) void qkv_transform(
    const unsigned short* __restrict__ qkv1,
    const unsigned short* __restrict__ qkv2,
    const float* __restrict__ qs1, const float* __restrict__ ks1,
    const float* __restrict__ qs2, const float* __restrict__ ks2,
    unsigned short* __restrict__ qO, unsigned short* __restrict__ kO,
    unsigned short* __restrict__ vO)
{
  const int row = blockIdx.x;
  const int lane = threadIdx.x & 63;
  const int wave = threadIdx.x >> 6;
  const float QSCALE = 0.18033688011112042f;  // 0.125 * log2(e)

  const unsigned short* src;
  const float* qs;
  const float* ks;
  int b, pos;
  if (row < BATCH * SEQ1) {
    b = row / SEQ1;
    pos = row % SEQ1;
    src = qkv1 + (size_t)row * (3 * D_MODEL);
    qs = qs1; ks = ks1;
  } else {
    int r2 = row - BATCH * SEQ1;
    b = r2 / SEQ2;
    pos = SEQ1 + (r2 % SEQ2);
    src = qkv2 + (size_t)r2 * (3 * D_MODEL);
    qs = qs2; ks = ks2;
  }

  const int j = lane >> 1;
  const float LOG2_THETA = 13.287712379549449f;
  float inv_freq = exp2f(-((float)(2 * j) / 64.0f) * LOG2_THETA);
  float ang = (float)pos * inv_freq;
  float sn, cs;
  sincosf(ang, &sn, &cs);

  for (int h = wave; h < N_HEADS; h += 4) {
    float xq = bf2f(src[0 * D_MODEL + h * HEAD_DIM + lane]);
    float xk = bf2f(src[1 * D_MODEL + h * HEAD_DIM + lane]);
    float xv = bf2f(src[2 * D_MODEL + h * HEAD_DIM + lane]);

    float sq = xq * xq, sk = xk * xk;
#pragma unroll
    for (int o = 32; o > 0; o >>= 1) {
      sq += __shfl_xor(sq, o);
      sk += __shfl_xor(sk, o);
    }
    float xqn = xq * rsqrtf(sq * (1.0f / 64.0f) + 1e-6f) * qs[lane];
    float xkn = xk * rsqrtf(sk * (1.0f / 64.0f) + 1e-6f) * ks[lane];

    float pq = __shfl_xor(xqn, 1);
    float pk = __shfl_xor(xkn, 1);
    float oq, ok;
    if (lane & 1) { oq = pq * sn + xqn * cs; ok = pk * sn + xkn * cs; }
    else          { oq = xqn * cs - pq * sn; ok = xkn * cs - pk * sn; }

    size_t o = (((size_t)b * N_HEADS + h) * NTOT + pos) * HEAD_DIM + lane;
    qO[o] = f2bf(oq * QSCALE);
    kO[o] = f2bf(ok);
    vO[o] = f2bf(xv);
  }
}

// ---------------------------------------------------------------------------
// V transpose: (BH, NTOT, 64) -> (BH, 64, NTOT), bf16, 64x64 tiles.
// ---------------------------------------------------------------------------
__global__ __launch_bounds__(256) void v_transpose(
    const unsigned short* __restrict__ v, unsigned short* __restrict__ vt)
{
  const int pt = blockIdx.x, bh = blockIdx.y;
  __shared__ unsigned short t[64][72];
  const int tid = threadIdx.x;
  const unsigned short* src = v + ((size_t)bh * NTOT + pt * 64) * 64;
#pragma unroll
  for (int c = 0; c < 2; ++c) {
    int off = c * 4096 + tid * 16;
    int row = off >> 7, c16 = (off & 127) >> 4;
    bf16x8 x = *(const bf16x8*)(src + row * 64 + c16 * 8);
#pragma unroll
    for (int j = 0; j < 8; ++j) t[row][c16 * 8 + j] = (unsigned short)x[j];
  }
  __syncthreads();
  unsigned short* dst = vt + (size_t)bh * 64 * NTOT + pt * 64;
#pragma unroll
  for (int c = 0; c < 2; ++c) {
    int off = c * 4096 + tid * 16;
    int d = off >> 7, p16 = (off & 127) >> 4;
    bf16x8 x;
#pragma unroll
    for (int j = 0; j < 8; ++j) x[j] = (short)t[p16 * 8 + j][d];
    *(bf16x8*)(dst + (size_t)d * NTOT + p16 * 8) = x;
  }
}

// ---------------------------------------------------------------------------
// MFMA flash attention, swapped-QK^T, QBLK=64 (this round: grid x2 for
// occupancy — 1024 blocks = 4/CU; LDS 40KB = 4/CU; was 2/CU grid-limited).
// S^T = mfma(K,Q): lane holds S[k = ct*16 + l4*4 + r][q = l15] -> scalar m/l
// per lane, 15-op local max + 2 shuffles, P packed to b64 LDS writes,
// row-sum from f32 p's. K/V dbuf + setprio kept from rounds 6/7.
// ---------------------------------------------------------------------------
__global__ __launch_bounds__(256) void attn_mfma(
    const unsigned short* __restrict__ Qg, const unsigned short* __restrict__ Kg,
    const unsigned short* __restrict__ VTg,
    unsigned short* __restrict__ xb1, unsigned short* __restrict__ xb2)
{
  const int qt = blockIdx.x, bh = blockIdx.y;
  const int b = bh >> 4, h = bh & 15;
  const int tid = threadIdx.x, lane = tid & 63, w = tid >> 6;
  const int l15 = lane & 15, l4 = lane >> 4;

  __shared__ __align__(16) unsigned short Klds[2][64 * 64];   // 2 x 8 KB
  __shared__ __align__(16) unsigned short Vlds[2][64 * 64];   // 2 x 8 KB
  __shared__ __align__(16) unsigned short Plds[64 * 64];      // 8 KB

  const size_t base = (size_t)bh * NTOT * HEAD_DIM;
  bf16x8 qf[2];
  {
    const unsigned short* qp =
        Qg + base + (size_t)(qt * 64 + w * 16 + l15) * 64 + l4 * 8;
    qf[0] = *(const bf16x8*)qp;
    qf[1] = *(const bf16x8*)(qp + 32);
  }

  f32x4 acc_o[4];
#pragma unroll
  for (int dt = 0; dt < 4; ++dt)
#pragma unroll
    for (int r = 0; r < 4; ++r) acc_o[dt][r] = 0.0f;
  float m_run = -1e30f, l_run = 0.0f;

  const unsigned short* kp = Kg + base;
  const unsigned short* vtp = VTg + (size_t)bh * HEAD_DIM * NTOT;

#define STAGE(bf, kt)                                                         \
  {                                                                           \
    _Pragma("unroll")                                                         \
    for (int c = 0; c < 2; ++c) {                                             \
      int off = c * 4096 + tid * 16;                                          \
      int row = off >> 7;                                                     \
      int c16g = ((off & 127) >> 4) ^ (row & 7);                              \
      int dstb = c * 4096 + (tid >> 6) * 1024;                                \
      gload16(kp + (size_t)((kt) * 64 + row) * 64 + c16g * 8,                 \
              (char*)Klds[bf] + dstb);                                        \
      gload16(vtp + (size_t)row * NTOT + (kt) * 64 + c16g * 8,                \
              (char*)Vlds[bf] + dstb);                                        \
    }                                                                         \
  }

  STAGE(0, 0);

  for (int kt = 0; kt < NTOT / 64; ++kt) {
    const int cur = kt & 1;
    __syncthreads();   // rendezvous + per-wave vmcnt drain: buf[cur] ready,
                       // all waves past their reads of buf[cur^1]
    if (kt + 1 < NTOT / 64) STAGE(cur ^ 1, kt + 1);

    // S^T = mfma(K, Q): sacc[ct][r] = S[k = ct*16 + l4*4 + r][q = l15]
    f32x4 sacc[4];
#pragma unroll
    for (int ct = 0; ct < 4; ++ct)
#pragma unroll
      for (int r = 0; r < 4; ++r) sacc[ct][r] = 0.0f;
    __builtin_amdgcn_s_setprio(1);
#pragma unroll
    for (int kk = 0; kk < 2; ++kk) {
#pragma unroll
      for (int ct = 0; ct < 4; ++ct) {
        int r = ct * 16 + l15;
        int colb = (kk * 64 + l4 * 16) ^ ((r & 7) << 4);
        bf16x8 kf = *(const bf16x8*)((const char*)Klds[cur] + r * 128 + colb);
        sacc[ct] = __builtin_amdgcn_mfma_f32_16x16x32_bf16(
            kf, qf[kk], sacc[ct], 0, 0, 0);
      }
    }
    __builtin_amdgcn_s_setprio(0);

    // softmax: each lane owns one q-column (q = l15)
    {
      float tm = fmaxf(fmaxf(sacc[0][0], sacc[0][1]),
                       fmaxf(sacc[0][2], sacc[0][3]));
#pragma unroll
      for (int ct = 1; ct < 4; ++ct)
        tm = fmaxf(tm, fmaxf(fmaxf(sacc[ct][0], sacc[ct][1]),
                             fmaxf(sacc[ct][2], sacc[ct][3])));
      tm = fmaxf(tm, __shfl_xor(tm, 16));
      tm = fmaxf(tm, __shfl_xor(tm, 32));
      float mo = m_run;
      if (!__all(tm <= mo + 8.0f)) {       // defer-max (THR=8, exp2 domain)
        float mn = fmaxf(mo, tm);
        float fac = exp2f(mo - mn);
        m_run = mn;
        l_run *= fac;
#pragma unroll
        for (int r = 0; r < 4; ++r) {
          float fr = __shfl(fac, l4 * 4 + r);
#pragma unroll
          for (int dt = 0; dt < 4; ++dt) acc_o[dt][r] *= fr;
        }
      }
      float mc = m_run;
      float rs = 0.0f;
      int qrow = w * 16 + l15;
#pragma unroll
      for (int ct = 0; ct < 4; ++ct) {
        float p0 = exp2f(sacc[ct][0] - mc);
        float p1 = exp2f(sacc[ct][1] - mc);
        float p2 = exp2f(sacc[ct][2] - mc);
        float p3 = exp2f(sacc[ct][3] - mc);
        rs += (p0 + p1) + (p2 + p3);
        uint2 pw;
        pw.x = (unsigned)f2bf(p0) | ((unsigned)f2bf(p1) << 16);
        pw.y = (unsigned)f2bf(p2) | ((unsigned)f2bf(p3) << 16);
        *(uint2*)((char*)Plds + qrow * 128 +
                  ((ct * 32 + l4 * 8) ^ ((qrow & 7) << 4))) = pw;
      }
      rs += __shfl_xor(rs, 16);
      rs += __shfl_xor(rs, 32);
      l_run += rs;
    }
    // no barrier: P rows are wave-private (same-wave DS ordering)

    // O += P @ V
    __builtin_amdgcn_s_setprio(1);
#pragma unroll
    for (int ks = 0; ks < 2; ++ks) {
      int pr = w * 16 + l15;
      int pcolb = (ks * 64 + l4 * 16) ^ ((pr & 7) << 4);
      bf16x8 pf = *(const bf16x8*)((const char*)Plds + pr * 128 + pcolb);
#pragma unroll
      for (int dt = 0; dt < 4; ++dt) {
        int vr = dt * 16 + l15;
        int vcolb = (ks * 64 + l4 * 16) ^ ((vr & 7) << 4);
        bf16x8 vf = *(const bf16x8*)((const char*)Vlds[cur] + vr * 128 + vcolb);
        acc_o[dt] = __builtin_amdgcn_mfma_f32_16x16x32_bf16(
            pf, vf, acc_o[dt], 0, 0, 0);
      }
    }
    __builtin_amdgcn_s_setprio(0);
  }
#undef STAGE

  {
    float inv = 1.0f / l_run;              // per q = l15
#pragma unroll
    for (int r = 0; r < 4; ++r) {
      float ir = __shfl(inv, l4 * 4 + r);
      int n = qt * 64 + w * 16 + l4 * 4 + r;
      unsigned short* dst;
      if (n < SEQ1) dst = xb1 + ((size_t)b * SEQ1 + n) * D_MODEL;
      else          dst = xb2 + ((size_t)b * SEQ2 + (n - SEQ1)) * D_MODEL;
#pragma unroll
      for (int dt = 0; dt < 4; ++dt)
        dst[h * 64 + dt * 16 + l15] = f2bf(acc_o[dt][r] * ir);
    }
  }
}

// ---------------------------------------------------------------------------
extern "C" void kernel_launch(void* const* d_in, const int* in_sizes, int n_in,
                              void* d_out, int out_size, void* d_ws,
                              size_t ws_size, hipStream_t stream)
{
  (void)in_sizes; (void)n_in; (void)out_size; (void)ws_size;

  const float* x1  = (const float*)d_in[0];
  const float* x2  = (const float*)d_in[1];
  const float* Wq1 = (const float*)d_in[2];
  const float* bq1 = (const float*)d_in[3];
  const float* Wq2 = (const float*)d_in[4];
  const float* bq2 = (const float*)d_in[5];
  const float* Wo1 = (const float*)d_in[6];
  const float* bo1 = (const float*)d_in[7];
  const float* Wo2 = (const float*)d_in[8];
  const float* bo2 = (const float*)d_in[9];
  const float* qs1 = (const float*)d_in[10];
  const float* ks1 = (const float*)d_in[11];
  const float* qs2 = (const float*)d_in[12];
  const float* ks2 = (const float*)d_in[13];
  float* out = (float*)d_out;

  unsigned short* ws = (unsigned short*)d_ws;
  const size_t SX1 = (size_t)BATCH * SEQ1 * D_MODEL;
  const size_t SX2 = (size_t)BATCH * SEQ2 * D_MODEL;
  const size_t SW  = (size_t)3 * D_MODEL * D_MODEL;
  const size_t SWO = (size_t)D_MODEL * D_MODEL;
  const size_t SQ1 = (size_t)BATCH * SEQ1 * 3 * D_MODEL;
  const size_t SQ2 = (size_t)BATCH * SEQ2 * 3 * D_MODEL;
  const size_t SH  = (size_t)BATCH * N_HEADS * NTOT * HEAD_DIM;

  unsigned short* x1b  = ws;
  unsigned short* x2b  = x1b + SX1;
  unsigned short* Wq1b = x2b + SX2;
  unsigned short* Wq2b = Wq1b + SW;
  unsigned short* Wo1b = Wq2b + SW;
  unsigned short* Wo2b = Wo1b + SWO;
  unsigned short* qkv1 = Wo2b + SWO;
  unsigned short* qkv2 = qkv1 + SQ1;
  unsigned short* qb   = qkv2 + SQ2;
  unsigned short* kb   = qb + SH;
  unsigned short* vb   = kb + SH;
  unsigned short* vtb  = vb + SH;
  unsigned short* xb1  = vtb + SH;          // (B,SEQ1,1024) bf16
  unsigned short* xb2  = xb1 + SX1;         // (B,SEQ2,1024) bf16

  // fused fp32 -> bf16 conversion
  CvtArgs ca;
  ca.src[0] = x1;  ca.dst[0] = x1b;
  ca.src[1] = x2;  ca.dst[1] = x2b;
  ca.src[2] = Wq1; ca.dst[2] = Wq1b;
  ca.src[3] = Wq2; ca.dst[3] = Wq2b;
  ca.src[4] = Wo1; ca.dst[4] = Wo1b;
  ca.src[5] = Wo2; ca.dst[5] = Wo2b;
  ca.prefix[0] = 0;
  ca.prefix[1] = (int)SX1;
  ca.prefix[2] = (int)(SX1 + SX2);
  ca.prefix[3] = (int)(SX1 + SX2 + SW);
  ca.prefix[4] = (int)(SX1 + SX2 + 2 * SW);
  ca.prefix[5] = (int)(SX1 + SX2 + 2 * SW + SWO);
  ca.prefix[6] = (int)(SX1 + SX2 + 2 * SW + 2 * SWO);
  cvt_all<<<(ca.prefix[6] / 4 + 255) / 256, 256, 0, stream>>>(ca);

  // QKV projections: one batched dispatch (bf16 out)
  {
    GemmSeg s0{x1b, Wq1b, bq1, qkv1, 3 * D_MODEL, D_MODEL, 3 * D_MODEL / 128};
    GemmSeg s1{x2b, Wq2b, bq2, qkv2, 3 * D_MODEL, D_MODEL, 3 * D_MODEL / 128};
    int t0 = (BATCH * SEQ1 / 128) * (3 * D_MODEL / 128);   // 576
    int t1 = (BATCH * SEQ2 / 128) * (3 * D_MODEL / 128);   // 192
    gemm2<1><<<t0 + t1, 256, 0, stream>>>(s0, s1, t0);
  }

  // RMSNorm + RoPE + scatter
  qkv_transform<<<BATCH * (SEQ1 + SEQ2), 256, 0, stream>>>(
      qkv1, qkv2, qs1, ks1, qs2, ks2, qb, kb, vb);

  // V transpose for PV operand
  v_transpose<<<dim3(NTOT / 64, BATCH * N_HEADS), 256, 0, stream>>>(vb, vtb);

  // attention (QBLK=64: 1024 blocks = 4/CU)
  attn_mfma<<<dim3(NTOT / 64, BATCH * N_HEADS), 256, 0, stream>>>(
      qb, kb, vtb, xb1, xb2);

  // output projections: one batched dispatch (f32 out)
  {
    GemmSeg s0{xb1, Wo1b, bo1, out, D_MODEL, D_MODEL, D_MODEL / 128};
    GemmSeg s1{xb2, Wo2b, bo2, out + (size_t)BATCH * SEQ1 * D_MODEL,
               D_MODEL, D_MODEL, D_MODEL / 128};
    int t0 = (BATCH * SEQ1 / 128) * (D_MODEL / 128);   // 192
    int t1 = (BATCH * SEQ2 / 128) * (D_MODEL / 128);   // 64
    gemm2<0><<<t0 + t1, 256, 0, stream>>>(s0, s1, t0);
  }
}